// Round 1
// 313.820 us; speedup vs baseline: 1.0475x; 1.0475x over previous
//
#include <hip/hip_runtime.h>
#include <math.h>

#define BB 4
#define SS 1024
#define DD 1024
#define HH 16
#define DHH 64

typedef _Float16 half8 __attribute__((ext_vector_type(8)));
typedef _Float16 half4v __attribute__((ext_vector_type(4)));
typedef float v4f __attribute__((ext_vector_type(4)));
typedef unsigned int u32;
typedef unsigned short u16;

// async global->LDS, 16B/lane. LDS dest is wave-uniform base + lane*16.
__device__ __forceinline__ void gload_lds16(const void* g, void* l) {
    __builtin_amdgcn_global_load_lds(
        (const __attribute__((address_space(1))) u32*)(const u32*)g,
        (__attribute__((address_space(3))) u32*)(u32*)l, 16, 0, 0);
}

// ---------------------------------------------------------------------------
// convert: W_q, W_k(*0.125), W_v, W_o, pe(*8)  fp32 -> f16  (verified)
// ---------------------------------------------------------------------------
__global__ __launch_bounds__(256) void convert_kernel(
    const float* __restrict__ wq, const float* __restrict__ wk,
    const float* __restrict__ wv, const float* __restrict__ wo,
    const float* __restrict__ pe, _Float16* __restrict__ dst)
{
    const int i4 = blockIdx.x * 256 + threadIdx.x;
    const int region = i4 >> 18;
    const int local4 = i4 & 262143;
    const float* srcs[5] = {wq, wk, wv, wo, pe};
    const float scales[5] = {1.0f, 0.125f, 1.0f, 1.0f, 8.0f};
    const float sc = scales[region];
    float4 v = *(const float4*)(srcs[region] + (size_t)local4 * 4);
    half4v h = {(_Float16)(v.x * sc), (_Float16)(v.y * sc),
                (_Float16)(v.z * sc), (_Float16)(v.w * sc)};
    *(half4v*)(dst + ((size_t)region << 20) + (size_t)local4 * 4) = h;
}

// ---------------------------------------------------------------------------
// Fused Q/K/V projection GEMMs (z = 0,1,2)  (R5-VERIFIED, twice; unchanged)
// ---------------------------------------------------------------------------
__global__ __launch_bounds__(256) void gemm_proj(
    const float* __restrict__ Aq, const float* __restrict__ Ak,
    const float* __restrict__ Av,
    const _Float16* __restrict__ Wqf, const _Float16* __restrict__ Wkf,
    const _Float16* __restrict__ Wvf,
    _Float16* __restrict__ Cq, _Float16* __restrict__ Ck,
    _Float16* __restrict__ Cv)
{
    __shared__ _Float16 As[128 * 32];
    __shared__ _Float16 Bs[64 * 32];

    const int z = blockIdx.z;
    const float* A = z == 0 ? Aq : z == 1 ? Ak : Av;
    const _Float16* W = z == 0 ? Wqf : z == 1 ? Wkf : Wvf;
    _Float16* C = z == 0 ? Cq : z == 1 ? Ck : Cv;

    const int tid = threadIdx.x;
    const int w = tid >> 6, lane = tid & 63, lm = lane & 15, quad = lane >> 4;
    const int n0 = blockIdx.x * 64, m0 = blockIdx.y * 128;

    const int brow = tid >> 2, blc = (tid & 3) ^ (brow & 3);

    v4f zero4 = {0.f, 0.f, 0.f, 0.f};
    v4f acc[2][4];
#pragma unroll
    for (int mi = 0; mi < 2; mi++)
#pragma unroll
        for (int ni = 0; ni < 4; ni++) acc[mi][ni] = zero4;

    for (int k0 = 0; k0 < DD; k0 += 32) {
        __syncthreads();
        gload_lds16(W + (size_t)(n0 + brow) * DD + k0 + blc * 8, Bs + tid * 8);
#pragma unroll
        for (int u = 0; u < 4; u++) {
            int c4 = tid + 256 * u;
            int row = c4 >> 3, k4 = c4 & 7;
            float4 v = *(const float4*)(A + (size_t)(m0 + row) * DD + k0 + k4 * 4);
            half4v hv = {(_Float16)v.x, (_Float16)v.y, (_Float16)v.z, (_Float16)v.w};
            int c16 = k4 >> 1, hlf = k4 & 1;
            *(half4v*)(As + row * 32 + (((c16 ^ (row & 3)) << 3) + (hlf << 2))) = hv;
        }
        __syncthreads();

        half8 af[2], bf[4];
#pragma unroll
        for (int mi = 0; mi < 2; mi++) {
            int row = w * 32 + mi * 16 + lm;
            af[mi] = *(const half8*)(As + row * 32 + ((quad ^ (row & 3)) << 3));
        }
#pragma unroll
        for (int ni = 0; ni < 4; ni++) {
            int row = ni * 16 + lm;
            bf[ni] = *(const half8*)(Bs + row * 32 + ((quad ^ (row & 3)) << 3));
        }
#pragma unroll
        for (int mi = 0; mi < 2; mi++)
#pragma unroll
            for (int ni = 0; ni < 4; ni++)
                acc[mi][ni] = __builtin_amdgcn_mfma_f32_16x16x32_f16(
                    af[mi], bf[ni], acc[mi][ni], 0, 0, 0);
    }

    const int h = n0 >> 6;
#pragma unroll
    for (int mi = 0; mi < 2; mi++)
#pragma unroll
        for (int r = 0; r < 4; r++) {
            int m = m0 + w * 32 + mi * 16 + quad * 4 + r;
            int b = m >> 10, s = m & 1023;
            size_t base = ((size_t)(b * HH + h) * SS + s) * DHH;
#pragma unroll
            for (int ni = 0; ni < 4; ni++)
                C[base + ni * 16 + lm] = (_Float16)acc[mi][ni][r];
        }
}

// ---------------------------------------------------------------------------
// Output GEMM: C(fp32 4096x1024) = A(f16) * W^T.  (R5-VERIFIED, twice; unchanged)
// ---------------------------------------------------------------------------
__global__ __launch_bounds__(256) void gemm_out(
    const _Float16* __restrict__ A, const _Float16* __restrict__ W,
    float* __restrict__ C)
{
    __shared__ _Float16 As[128 * 32];
    __shared__ _Float16 Bs[64 * 32];

    const int tid = threadIdx.x;
    const int w = tid >> 6, lane = tid & 63, lm = lane & 15, quad = lane >> 4;
    const int n0 = blockIdx.x * 64, m0 = blockIdx.y * 128;
    const int brow = tid >> 2, blc = (tid & 3) ^ (brow & 3);

    v4f zero4 = {0.f, 0.f, 0.f, 0.f};
    v4f acc[2][4];
#pragma unroll
    for (int mi = 0; mi < 2; mi++)
#pragma unroll
        for (int ni = 0; ni < 4; ni++) acc[mi][ni] = zero4;

    for (int k0 = 0; k0 < DD; k0 += 32) {
        __syncthreads();
        gload_lds16(W + (size_t)(n0 + brow) * DD + k0 + blc * 8, Bs + tid * 8);
#pragma unroll
        for (int u = 0; u < 2; u++) {
            int p = tid + 256 * u;
            int row = p >> 2, lc = (p & 3) ^ (row & 3);
            gload_lds16(A + (size_t)(m0 + row) * DD + k0 + lc * 8, As + p * 8);
        }
        __syncthreads();

        half8 af[2], bf[4];
#pragma unroll
        for (int mi = 0; mi < 2; mi++) {
            int row = w * 32 + mi * 16 + lm;
            af[mi] = *(const half8*)(As + row * 32 + ((quad ^ (row & 3)) << 3));
        }
#pragma unroll
        for (int ni = 0; ni < 4; ni++) {
            int row = ni * 16 + lm;
            bf[ni] = *(const half8*)(Bs + row * 32 + ((quad ^ (row & 3)) << 3));
        }
#pragma unroll
        for (int mi = 0; mi < 2; mi++)
#pragma unroll
            for (int ni = 0; ni < 4; ni++)
                acc[mi][ni] = __builtin_amdgcn_mfma_f32_16x16x32_f16(
                    af[mi], bf[ni], acc[mi][ni], 0, 0, 0);
    }

#pragma unroll
    for (int mi = 0; mi < 2; mi++)
#pragma unroll
        for (int r = 0; r < 4; r++) {
            size_t base = (size_t)(m0 + w * 32 + mi * 16 + quad * 4 + r) * DD
                        + n0 + lm;
#pragma unroll
            for (int ni = 0; ni < 4; ni++)
                C[base + ni * 16] = acc[mi][ni][r];
        }
}

// ---------------------------------------------------------------------------
// MFMA flash attention — R7: three targeted changes on the verified R6+A
// kernel (counters: MfmaUtil 6.5%, Occupancy 18.5%, LDS_BANK_CONFLICT 2.1e7):
//  1) Qs LDS buffer deleted; qf fragments loaded directly from global (Q is
//     L2-resident, read once per block).  LDS 55.3KB -> 45KB => 3 blocks/CU
//     (12 waves/CU vs 8).
//  2) Vt XOR-swizzle: element (d,j) stored at d*72 + (j ^ (((d>>3)&7)<<3)).
//     Fixes the 8-way bank conflict of the scalar transpose writes (old:
//     k8-stride 8*72 halves = 288 words == 0 mod 32 -> 8 lanes/bank on 4
//     banks).  New write banks: 4*((e+((w+4u)^k8))&7) + r/2 -> all 32 banks,
//     2-way max (free).  XOR touches only column bits 3-5, so the contiguous
//     half8 PV fragment reads are preserved (bijective per row => exact).
//  3) s_setprio(1) around MFMA clusters (attn-verified +4-7% when blocks
//     are desynced, which 3 blocks/CU guarantees).
// Everything else (5-tile PE band + shfl diagonal gather, dedicated P
// buffer, barriers a/b/e, padded stride-72 LDS) is verbatim.
// ---------------------------------------------------------------------------
__global__ __launch_bounds__(256) void attn_mfma(
    const _Float16* __restrict__ Qg, const _Float16* __restrict__ Kg,
    const _Float16* __restrict__ Vg, const int* __restrict__ mask,
    const _Float16* __restrict__ peg, _Float16* __restrict__ Og)
{
    __shared__ _Float16 Ks[64 * 72];        // 9 KB  padded
    __shared__ _Float16 Vt[64 * 72];        // 9 KB  [d][j^swz], padded
    __shared__ _Float16 PEb[128 * 72];      // 18 KB [o][d], padded
    __shared__ _Float16 Pb[4][16 * 72];     // 9 KB  per-wave P (dedicated)

    const int tid = threadIdx.x;
    const int w = tid >> 6, lane = tid & 63;
    const int lm = lane & 15, quad = lane >> 4;
    const int it = blockIdx.x, i0 = it * 64;
    const int bh = blockIdx.y, b = bh >> 4, h = bh & 15;

    const _Float16* Qb = Qg + (size_t)bh * SS * DHH;
    const _Float16* Kb = Kg + (size_t)bh * SS * DHH;
    const _Float16* Vb = Vg + (size_t)bh * SS * DHH;
    const _Float16* peh = peg + (size_t)h * SS * DHH;

    float mi_f[4];
#pragma unroll
    for (int r = 0; r < 4; r++)
        mi_f[r] = (float)mask[b * SS + i0 + w * 16 + quad * 4 + r];

    // loop-invariant Q fragments, straight from global (L2-resident)
    half8 qf[2];
#pragma unroll
    for (int kc = 0; kc < 2; kc++)
        qf[kc] = *(const half8*)(Qb + (size_t)(i0 + w * 16 + lm) * DHH
                                 + kc * 32 + quad * 8);

    v4f zero4 = {0.f, 0.f, 0.f, 0.f};
    float m_run[4], l_run[4];
    v4f oacc[4];
#pragma unroll
    for (int r = 0; r < 4; r++) { m_run[r] = -1e30f; l_run[r] = 0.f; }
#pragma unroll
    for (int nb = 0; nb < 4; nb++) oacc[nb] = zero4;

    for (int jt = 0; jt < SS / 64; jt++) {
        const int j0 = jt * 64;
        const bool do_pe = (jt <= it);
        __syncthreads();                                   // (a) prev-iter reads done

        // stage K (manual, padded)  [verbatim]
#pragma unroll
        for (int u = 0; u < 2; u++) {
            int c = tid + 256 * u;
            int row = c >> 3, k8 = c & 7;
            half8 v = *(const half8*)(Kb + (size_t)(j0 + row) * DHH + k8 * 8);
            *(half8*)(Ks + row * 72 + k8 * 8) = v;
        }
        // stage V transposed, XOR-swizzled column (conflict-free writes)
#pragma unroll
        for (int u = 0; u < 2; u++) {
            int c = tid + 256 * u;
            int row = c >> 3, k8 = c & 7;
            half8 v = *(const half8*)(Vb + (size_t)(j0 + row) * DHH + k8 * 8);
            int jsw = row ^ (k8 << 3);                     // (d>>3)&7 == k8 for all e
#pragma unroll
            for (int e = 0; e < 8; e++) Vt[(k8 * 8 + e) * 72 + jsw] = v[e];
        }
        // stage PE band (128 rows x 64; zero-fill OOB)  [verbatim]
        if (do_pe) {
            const int g0 = SS - 1 + j0 - i0 - 63;          // in [0, 960]
#pragma unroll
            for (int u = 0; u < 4; u++) {
                int c = tid + 256 * u;
                int o = c >> 3, k8 = c & 7;
                int g = g0 + o;
                half8 v = {0, 0, 0, 0, 0, 0, 0, 0};
                if (g < SS) v = *(const half8*)(peh + (size_t)g * DHH + k8 * 8);
                *(half8*)(PEb + o * 72 + k8 * 8) = v;
            }
        }
        float mj_f[4];
#pragma unroll
        for (int nb = 0; nb < 4; nb++)
            mj_f[nb] = (float)mask[b * SS + j0 + nb * 16 + lm];
        __syncthreads();                                   // (b) staging visible

        // ---- QK^T  [verbatim]
        v4f sacc[4];
#pragma unroll
        for (int nb = 0; nb < 4; nb++) sacc[nb] = zero4;
        __builtin_amdgcn_s_setprio(1);
#pragma unroll
        for (int nb = 0; nb < 4; nb++)
#pragma unroll
            for (int kc = 0; kc < 2; kc++) {
                half8 kf = *(const half8*)(Ks + (nb * 16 + lm) * 72 + kc * 32 + quad * 8);
                sacc[nb] = __builtin_amdgcn_mfma_f32_16x16x32_f16(qf[kc], kf, sacc[nb], 0, 0, 0);
            }
        __builtin_amdgcn_s_setprio(0);

        // ---- relative position band: 5 tiles + shfl gather  [verbatim]
        if (do_pe) {
            v4f racc[5];
#pragma unroll
            for (int e = 0; e < 5; e++) racc[e] = zero4;
            __builtin_amdgcn_s_setprio(1);
#pragma unroll
            for (int e = 0; e < 5; e++) {
                int row = (e + 3 - w) * 16 + lm;
#pragma unroll
                for (int kc = 0; kc < 2; kc++) {
                    half8 pf = *(const half8*)(PEb + row * 72 + kc * 32 + quad * 8);
                    racc[e] = __builtin_amdgcn_mfma_f32_16x16x32_f16(qf[kc], pf, racc[e], 0, 0, 0);
                }
            }
            __builtin_amdgcn_s_setprio(0);
#pragma unroll
            for (int nb = 0; nb < 4; nb++)
#pragma unroll
                for (int r = 0; r < 4; r++) {
                    int qr = quad * 4 + r;
                    float vsrc = (((lm + qr + 1) & 15) <= qr)
                               ? racc[nb][r] : racc[nb + 1][r];
                    int src = (lane & 48) | ((lm - qr - 1) & 15);
                    sacc[nb][r] += __shfl(vsrc, src);
                }
        }

        // ---- mask + online softmax  [verbatim]
        float p[4][4];
        float alpha[4];
#pragma unroll
        for (int i = 0; i < 4; i++) {
            float mi = mi_f[i];
            float rmax = -1e30f;
#pragma unroll
            for (int j = 0; j < 4; j++) {
                float s = sacc[j][i];
                if (mi * mj_f[j] == 0.f) s = -1e9f;
                sacc[j][i] = s;
                rmax = fmaxf(rmax, s);
            }
#pragma unroll
            for (int off = 1; off < 16; off <<= 1)
                rmax = fmaxf(rmax, __shfl_xor(rmax, off));
            float mnew = fmaxf(m_run[i], rmax);
            alpha[i] = __expf(m_run[i] - mnew);
            m_run[i] = mnew;
            float rsum = 0.f;
#pragma unroll
            for (int j = 0; j < 4; j++) {
                p[j][i] = __expf(sacc[j][i] - mnew);
                rsum += p[j][i];
            }
#pragma unroll
            for (int off = 1; off < 16; off <<= 1)
                rsum += __shfl_xor(rsum, off);
            l_run[i] = l_run[i] * alpha[i] + rsum;
        }

        // write P (f16) into dedicated per-wave buffer; rescale O
        _Float16* Pw = &Pb[w][0];
#pragma unroll
        for (int nb = 0; nb < 4; nb++)
#pragma unroll
            for (int r = 0; r < 4; r++)
                Pw[(quad * 4 + r) * 72 + nb * 16 + lm] = (_Float16)p[nb][r];
#pragma unroll
        for (int nb = 0; nb < 4; nb++)
#pragma unroll
            for (int r = 0; r < 4; r++) oacc[nb][r] *= alpha[r];
        __syncthreads();                                   // (e) P visible

        // ---- PV (Vt reads use the matching XOR on column bits 3-5)
        __builtin_amdgcn_s_setprio(1);
#pragma unroll
        for (int kc = 0; kc < 2; kc++) {
            half8 pfrag = *(const half8*)(Pw + lm * 72 + kc * 32 + quad * 8);
#pragma unroll
            for (int nb = 0; nb < 4; nb++) {
                int d = nb * 16 + lm;
                int col = (kc * 32 + quad * 8) ^ (((d >> 3) & 7) << 3);
                half8 vfrag = *(const half8*)(Vt + d * 72 + col);
                oacc[nb] = __builtin_amdgcn_mfma_f32_16x16x32_f16(pfrag, vfrag, oacc[nb], 0, 0, 0);
            }
        }
        __builtin_amdgcn_s_setprio(0);
    }

    // epilogue: normalize, write f16 [B,S,D]
#pragma unroll
    for (int r = 0; r < 4; r++) {
        float inv = 1.f / l_run[r];
        int s = i0 + w * 16 + quad * 4 + r;
#pragma unroll
        for (int nb = 0; nb < 4; nb++)
            Og[((size_t)b * SS + s) * DD + h * DHH + nb * 16 + lm] =
                (_Float16)(oacc[nb][r] * inv);
    }
}

extern "C" void kernel_launch(void* const* d_in, const int* in_sizes, int n_in,
                              void* d_out, int out_size, void* d_ws, size_t ws_size,
                              hipStream_t stream)
{
    const float* query = (const float*)d_in[0];
    const float* key   = (const float*)d_in[1];
    const float* value = (const float*)d_in[2];
    const int*   mask  = (const int*)d_in[3];
    const float* pe    = (const float*)d_in[4];
    const float* Wq    = (const float*)d_in[5];
    const float* Wk    = (const float*)d_in[6];
    const float* Wv    = (const float*)d_in[7];
    const float* Wo    = (const float*)d_in[8];
    float* out = (float*)d_out;

    _Float16* ws16 = (_Float16*)d_ws;
    const size_t MEG = 1048576;
    _Float16* wqf = ws16;
    _Float16* wkf = ws16 + 1 * MEG;
    _Float16* wvf = ws16 + 2 * MEG;
    _Float16* wof = ws16 + 3 * MEG;
    _Float16* pef = ws16 + 4 * MEG;
    _Float16* qp  = ws16 + 5 * MEG;     // [B,H,S,DH]
    _Float16* kp  = ws16 + 9 * MEG;     // [B,H,S,DH]
    _Float16* vp  = ws16 + 13 * MEG;    // [B,H,S,DH]
    _Float16* ao  = ws16 + 17 * MEG;    // [B,S,D]

    convert_kernel<<<5120, 256, 0, stream>>>(Wq, Wk, Wv, Wo, pe, ws16);

    gemm_proj<<<dim3(DD / 64, (BB * SS) / 128, 3), 256, 0, stream>>>(
        query, key, value, wqf, wkf, wvf, qp, kp, vp);

    attn_mfma<<<dim3(SS / 64, BB * HH), 256, 0, stream>>>(qp, kp, vp, mask, pef, ao);

    gemm_out<<<dim3(DD / 64, (BB * SS) / 128), 256, 0, stream>>>(ao, wof, out);
}

// Round 2
// 306.622 us; speedup vs baseline: 1.0721x; 1.0235x over previous
//
#include <hip/hip_runtime.h>
#include <math.h>

#define BB 4
#define SS 1024
#define DD 1024
#define HH 16
#define DHH 64

typedef _Float16 half8 __attribute__((ext_vector_type(8)));
typedef _Float16 half4v __attribute__((ext_vector_type(4)));
typedef float v4f __attribute__((ext_vector_type(4)));
typedef unsigned int u32;
typedef unsigned short u16;

// async global->LDS, 16B/lane. LDS dest is wave-uniform base + lane*16.
__device__ __forceinline__ void gload_lds16(const void* g, void* l) {
    __builtin_amdgcn_global_load_lds(
        (const __attribute__((address_space(1))) u32*)(const u32*)g,
        (__attribute__((address_space(3))) u32*)(u32*)l, 16, 0, 0);
}

// ---------------------------------------------------------------------------
// convert: W_q, W_k(*0.125), W_v, W_o, pe(*8)  fp32 -> f16  (verified)
// ---------------------------------------------------------------------------
__global__ __launch_bounds__(256) void convert_kernel(
    const float* __restrict__ wq, const float* __restrict__ wk,
    const float* __restrict__ wv, const float* __restrict__ wo,
    const float* __restrict__ pe, _Float16* __restrict__ dst)
{
    const int i4 = blockIdx.x * 256 + threadIdx.x;
    const int region = i4 >> 18;
    const int local4 = i4 & 262143;
    const float* srcs[5] = {wq, wk, wv, wo, pe};
    const float scales[5] = {1.0f, 0.125f, 1.0f, 1.0f, 8.0f};
    const float sc = scales[region];
    float4 v = *(const float4*)(srcs[region] + (size_t)local4 * 4);
    half4v h = {(_Float16)(v.x * sc), (_Float16)(v.y * sc),
                (_Float16)(v.z * sc), (_Float16)(v.w * sc)};
    *(half4v*)(dst + ((size_t)region << 20) + (size_t)local4 * 4) = h;
}

// ---------------------------------------------------------------------------
// Fused Q/K/V projection GEMMs (z = 0,1,2)  (R5-VERIFIED, twice; unchanged)
// ---------------------------------------------------------------------------
__global__ __launch_bounds__(256) void gemm_proj(
    const float* __restrict__ Aq, const float* __restrict__ Ak,
    const float* __restrict__ Av,
    const _Float16* __restrict__ Wqf, const _Float16* __restrict__ Wkf,
    const _Float16* __restrict__ Wvf,
    _Float16* __restrict__ Cq, _Float16* __restrict__ Ck,
    _Float16* __restrict__ Cv)
{
    __shared__ _Float16 As[128 * 32];
    __shared__ _Float16 Bs[64 * 32];

    const int z = blockIdx.z;
    const float* A = z == 0 ? Aq : z == 1 ? Ak : Av;
    const _Float16* W = z == 0 ? Wqf : z == 1 ? Wkf : Wvf;
    _Float16* C = z == 0 ? Cq : z == 1 ? Ck : Cv;

    const int tid = threadIdx.x;
    const int w = tid >> 6, lane = tid & 63, lm = lane & 15, quad = lane >> 4;
    const int n0 = blockIdx.x * 64, m0 = blockIdx.y * 128;

    const int brow = tid >> 2, blc = (tid & 3) ^ (brow & 3);

    v4f zero4 = {0.f, 0.f, 0.f, 0.f};
    v4f acc[2][4];
#pragma unroll
    for (int mi = 0; mi < 2; mi++)
#pragma unroll
        for (int ni = 0; ni < 4; ni++) acc[mi][ni] = zero4;

    for (int k0 = 0; k0 < DD; k0 += 32) {
        __syncthreads();
        gload_lds16(W + (size_t)(n0 + brow) * DD + k0 + blc * 8, Bs + tid * 8);
#pragma unroll
        for (int u = 0; u < 4; u++) {
            int c4 = tid + 256 * u;
            int row = c4 >> 3, k4 = c4 & 7;
            float4 v = *(const float4*)(A + (size_t)(m0 + row) * DD + k0 + k4 * 4);
            half4v hv = {(_Float16)v.x, (_Float16)v.y, (_Float16)v.z, (_Float16)v.w};
            int c16 = k4 >> 1, hlf = k4 & 1;
            *(half4v*)(As + row * 32 + (((c16 ^ (row & 3)) << 3) + (hlf << 2))) = hv;
        }
        __syncthreads();

        half8 af[2], bf[4];
#pragma unroll
        for (int mi = 0; mi < 2; mi++) {
            int row = w * 32 + mi * 16 + lm;
            af[mi] = *(const half8*)(As + row * 32 + ((quad ^ (row & 3)) << 3));
        }
#pragma unroll
        for (int ni = 0; ni < 4; ni++) {
            int row = ni * 16 + lm;
            bf[ni] = *(const half8*)(Bs + row * 32 + ((quad ^ (row & 3)) << 3));
        }
#pragma unroll
        for (int mi = 0; mi < 2; mi++)
#pragma unroll
            for (int ni = 0; ni < 4; ni++)
                acc[mi][ni] = __builtin_amdgcn_mfma_f32_16x16x32_f16(
                    af[mi], bf[ni], acc[mi][ni], 0, 0, 0);
    }

    const int h = n0 >> 6;
#pragma unroll
    for (int mi = 0; mi < 2; mi++)
#pragma unroll
        for (int r = 0; r < 4; r++) {
            int m = m0 + w * 32 + mi * 16 + quad * 4 + r;
            int b = m >> 10, s = m & 1023;
            size_t base = ((size_t)(b * HH + h) * SS + s) * DHH;
#pragma unroll
            for (int ni = 0; ni < 4; ni++)
                C[base + ni * 16 + lm] = (_Float16)acc[mi][ni][r];
        }
}

// ---------------------------------------------------------------------------
// Output GEMM: C(fp32 4096x1024) = A(f16) * W^T.  (R5-VERIFIED, twice; unchanged)
// ---------------------------------------------------------------------------
__global__ __launch_bounds__(256) void gemm_out(
    const _Float16* __restrict__ A, const _Float16* __restrict__ W,
    float* __restrict__ C)
{
    __shared__ _Float16 As[128 * 32];
    __shared__ _Float16 Bs[64 * 32];

    const int tid = threadIdx.x;
    const int w = tid >> 6, lane = tid & 63, lm = lane & 15, quad = lane >> 4;
    const int n0 = blockIdx.x * 64, m0 = blockIdx.y * 128;
    const int brow = tid >> 2, blc = (tid & 3) ^ (brow & 3);

    v4f zero4 = {0.f, 0.f, 0.f, 0.f};
    v4f acc[2][4];
#pragma unroll
    for (int mi = 0; mi < 2; mi++)
#pragma unroll
        for (int ni = 0; ni < 4; ni++) acc[mi][ni] = zero4;

    for (int k0 = 0; k0 < DD; k0 += 32) {
        __syncthreads();
        gload_lds16(W + (size_t)(n0 + brow) * DD + k0 + blc * 8, Bs + tid * 8);
#pragma unroll
        for (int u = 0; u < 2; u++) {
            int p = tid + 256 * u;
            int row = p >> 2, lc = (p & 3) ^ (row & 3);
            gload_lds16(A + (size_t)(m0 + row) * DD + k0 + lc * 8, As + p * 8);
        }
        __syncthreads();

        half8 af[2], bf[4];
#pragma unroll
        for (int mi = 0; mi < 2; mi++) {
            int row = w * 32 + mi * 16 + lm;
            af[mi] = *(const half8*)(As + row * 32 + ((quad ^ (row & 3)) << 3));
        }
#pragma unroll
        for (int ni = 0; ni < 4; ni++) {
            int row = ni * 16 + lm;
            bf[ni] = *(const half8*)(Bs + row * 32 + ((quad ^ (row & 3)) << 3));
        }
#pragma unroll
        for (int mi = 0; mi < 2; mi++)
#pragma unroll
            for (int ni = 0; ni < 4; ni++)
                acc[mi][ni] = __builtin_amdgcn_mfma_f32_16x16x32_f16(
                    af[mi], bf[ni], acc[mi][ni], 0, 0, 0);
    }

#pragma unroll
    for (int mi = 0; mi < 2; mi++)
#pragma unroll
        for (int r = 0; r < 4; r++) {
            size_t base = (size_t)(m0 + w * 32 + mi * 16 + quad * 4 + r) * DD
                        + n0 + lm;
#pragma unroll
            for (int ni = 0; ni < 4; ni++)
                C[base + ni * 16] = acc[mi][ni][r];
        }
}

// ---------------------------------------------------------------------------
// MFMA flash attention — R8: two structural changes on the verified R7 kernel
// (counters: MfmaUtil 7.3%, VALUBusy 32%, Occ 21%, conflicts 6.1e6):
//  1) T14 async-STAGE split: tile jt+1's K/V/PE global loads are issued into
//     REGISTERS right after barrier (b), before the compute phase; the
//     vmcnt drain lands at the ds_write after the NEXT barrier (a).  The
//     ~300-cyc L2 latency that previously sat exposed between barriers
//     every iteration is now hidden under QK^T/softmax/PV.
//  2) barrier (e) deleted: Pb[w] is per-wave (written and read by the same
//     wave only); same-wave LDS RAW is ordered by compiler-inserted
//     lgkmcnt, no block barrier required.  2 barriers/iter instead of 3.
// Everything else (5-tile PE band + shfl diagonal gather, Vt XOR-swizzle,
// padded stride-72 LDS, setprio around MFMA clusters) is R7 verbatim.
// ---------------------------------------------------------------------------
__global__ __launch_bounds__(256) void attn_mfma(
    const _Float16* __restrict__ Qg, const _Float16* __restrict__ Kg,
    const _Float16* __restrict__ Vg, const int* __restrict__ mask,
    const _Float16* __restrict__ peg, _Float16* __restrict__ Og)
{
    __shared__ _Float16 Ks[64 * 72];        // 9 KB  padded
    __shared__ _Float16 Vt[64 * 72];        // 9 KB  [d][j^swz], padded
    __shared__ _Float16 PEb[128 * 72];      // 18 KB [o][d], padded
    __shared__ _Float16 Pb[4][16 * 72];     // 9 KB  per-wave P (dedicated)

    const int tid = threadIdx.x;
    const int w = tid >> 6, lane = tid & 63;
    const int lm = lane & 15, quad = lane >> 4;
    const int it = blockIdx.x, i0 = it * 64;
    const int bh = blockIdx.y, b = bh >> 4, h = bh & 15;

    const _Float16* Qb = Qg + (size_t)bh * SS * DHH;
    const _Float16* Kb = Kg + (size_t)bh * SS * DHH;
    const _Float16* Vb = Vg + (size_t)bh * SS * DHH;
    const _Float16* peh = peg + (size_t)h * SS * DHH;

    float mi_f[4];
#pragma unroll
    for (int r = 0; r < 4; r++)
        mi_f[r] = (float)mask[b * SS + i0 + w * 16 + quad * 4 + r];

    // loop-invariant Q fragments, straight from global (L2-resident)
    half8 qf[2];
#pragma unroll
    for (int kc = 0; kc < 2; kc++)
        qf[kc] = *(const half8*)(Qb + (size_t)(i0 + w * 16 + lm) * DHH
                                 + kc * 32 + quad * 8);

    // per-thread staging indices (same for K/V; PE uses 4 chunks)
    const int srow = tid >> 3, sk8 = tid & 7;   // chunk 0; chunk 1 adds +32 rows

    v4f zero4 = {0.f, 0.f, 0.f, 0.f};
    float m_run[4], l_run[4];
    v4f oacc[4];
#pragma unroll
    for (int r = 0; r < 4; r++) { m_run[r] = -1e30f; l_run[r] = 0.f; }
#pragma unroll
    for (int nb = 0; nb < 4; nb++) oacc[nb] = zero4;

    // ---- prologue prefetch for jt = 0 (do_pe(0) == true always)
    half8 kreg[2], vreg[2], pereg[4];
#pragma unroll
    for (int u = 0; u < 2; u++) {
        int row = srow + 32 * u;
        kreg[u] = *(const half8*)(Kb + (size_t)row * DHH + sk8 * 8);
        vreg[u] = *(const half8*)(Vb + (size_t)row * DHH + sk8 * 8);
    }
    {
        const int g0 = SS - 1 - i0 - 63;               // jt = 0
#pragma unroll
        for (int u = 0; u < 4; u++) {
            int o = srow + 32 * u;
            int g = g0 + o;
            half8 v = {0, 0, 0, 0, 0, 0, 0, 0};
            if (g < SS) v = *(const half8*)(peh + (size_t)g * DHH + sk8 * 8);
            pereg[u] = v;
        }
    }

    for (int jt = 0; jt < SS / 64; jt++) {
        const int j0 = jt * 64;
        const bool do_pe = (jt <= it);
        __syncthreads();                                   // (a) prev-iter reads done

        // ---- commit prefetched regs to LDS (vmcnt wait lands here)
#pragma unroll
        for (int u = 0; u < 2; u++) {
            int row = srow + 32 * u;
            *(half8*)(Ks + row * 72 + sk8 * 8) = kreg[u];
        }
#pragma unroll
        for (int u = 0; u < 2; u++) {
            int row = srow + 32 * u;
            int jsw = row ^ (sk8 << 3);                    // Vt XOR-swizzle
#pragma unroll
            for (int e = 0; e < 8; e++) Vt[(sk8 * 8 + e) * 72 + jsw] = vreg[u][e];
        }
        if (do_pe) {
#pragma unroll
            for (int u = 0; u < 4; u++) {
                int o = srow + 32 * u;
                *(half8*)(PEb + o * 72 + sk8 * 8) = pereg[u];
            }
        }
        float mj_f[4];
#pragma unroll
        for (int nb = 0; nb < 4; nb++)
            mj_f[nb] = (float)mask[b * SS + j0 + nb * 16 + lm];
        __syncthreads();                                   // (b) staging visible

        // ---- prefetch tile jt+1 into regs (latency hidden under compute)
        if (jt + 1 < SS / 64) {
            const int j0n = j0 + 64;
#pragma unroll
            for (int u = 0; u < 2; u++) {
                int row = srow + 32 * u;
                kreg[u] = *(const half8*)(Kb + (size_t)(j0n + row) * DHH + sk8 * 8);
                vreg[u] = *(const half8*)(Vb + (size_t)(j0n + row) * DHH + sk8 * 8);
            }
            if (jt + 1 <= it) {
                const int g0n = SS - 1 + j0n - i0 - 63;
#pragma unroll
                for (int u = 0; u < 4; u++) {
                    int o = srow + 32 * u;
                    int g = g0n + o;
                    half8 v = {0, 0, 0, 0, 0, 0, 0, 0};
                    if (g < SS) v = *(const half8*)(peh + (size_t)g * DHH + sk8 * 8);
                    pereg[u] = v;
                }
            }
        }

        // ---- QK^T  [verbatim]
        v4f sacc[4];
#pragma unroll
        for (int nb = 0; nb < 4; nb++) sacc[nb] = zero4;
        __builtin_amdgcn_s_setprio(1);
#pragma unroll
        for (int nb = 0; nb < 4; nb++)
#pragma unroll
            for (int kc = 0; kc < 2; kc++) {
                half8 kf = *(const half8*)(Ks + (nb * 16 + lm) * 72 + kc * 32 + quad * 8);
                sacc[nb] = __builtin_amdgcn_mfma_f32_16x16x32_f16(qf[kc], kf, sacc[nb], 0, 0, 0);
            }
        __builtin_amdgcn_s_setprio(0);

        // ---- relative position band: 5 tiles + shfl gather  [verbatim]
        if (do_pe) {
            v4f racc[5];
#pragma unroll
            for (int e = 0; e < 5; e++) racc[e] = zero4;
            __builtin_amdgcn_s_setprio(1);
#pragma unroll
            for (int e = 0; e < 5; e++) {
                int row = (e + 3 - w) * 16 + lm;
#pragma unroll
                for (int kc = 0; kc < 2; kc++) {
                    half8 pf = *(const half8*)(PEb + row * 72 + kc * 32 + quad * 8);
                    racc[e] = __builtin_amdgcn_mfma_f32_16x16x32_f16(qf[kc], pf, racc[e], 0, 0, 0);
                }
            }
            __builtin_amdgcn_s_setprio(0);
#pragma unroll
            for (int nb = 0; nb < 4; nb++)
#pragma unroll
                for (int r = 0; r < 4; r++) {
                    int qr = quad * 4 + r;
                    float vsrc = (((lm + qr + 1) & 15) <= qr)
                               ? racc[nb][r] : racc[nb + 1][r];
                    int src = (lane & 48) | ((lm - qr - 1) & 15);
                    sacc[nb][r] += __shfl(vsrc, src);
                }
        }

        // ---- mask + online softmax  [verbatim]
        float p[4][4];
        float alpha[4];
#pragma unroll
        for (int i = 0; i < 4; i++) {
            float mi = mi_f[i];
            float rmax = -1e30f;
#pragma unroll
            for (int j = 0; j < 4; j++) {
                float s = sacc[j][i];
                if (mi * mj_f[j] == 0.f) s = -1e9f;
                sacc[j][i] = s;
                rmax = fmaxf(rmax, s);
            }
#pragma unroll
            for (int off = 1; off < 16; off <<= 1)
                rmax = fmaxf(rmax, __shfl_xor(rmax, off));
            float mnew = fmaxf(m_run[i], rmax);
            alpha[i] = __expf(m_run[i] - mnew);
            m_run[i] = mnew;
            float rsum = 0.f;
#pragma unroll
            for (int j = 0; j < 4; j++) {
                p[j][i] = __expf(sacc[j][i] - mnew);
                rsum += p[j][i];
            }
#pragma unroll
            for (int off = 1; off < 16; off <<= 1)
                rsum += __shfl_xor(rsum, off);
            l_run[i] = l_run[i] * alpha[i] + rsum;
        }

        // write P (f16) into dedicated per-wave buffer; rescale O.
        // NO block barrier needed: Pb[w] is written+read by wave w only;
        // same-wave LDS RAW is ordered via lgkmcnt.
        _Float16* Pw = &Pb[w][0];
#pragma unroll
        for (int nb = 0; nb < 4; nb++)
#pragma unroll
            for (int r = 0; r < 4; r++)
                Pw[(quad * 4 + r) * 72 + nb * 16 + lm] = (_Float16)p[nb][r];
#pragma unroll
        for (int nb = 0; nb < 4; nb++)
#pragma unroll
            for (int r = 0; r < 4; r++) oacc[nb][r] *= alpha[r];

        // ---- PV (Vt reads use the matching XOR on column bits 3-5)
        __builtin_amdgcn_s_setprio(1);
#pragma unroll
        for (int kc = 0; kc < 2; kc++) {
            half8 pfrag = *(const half8*)(Pw + lm * 72 + kc * 32 + quad * 8);
#pragma unroll
            for (int nb = 0; nb < 4; nb++) {
                int d = nb * 16 + lm;
                int col = (kc * 32 + quad * 8) ^ (((d >> 3) & 7) << 3);
                half8 vfrag = *(const half8*)(Vt + d * 72 + col);
                oacc[nb] = __builtin_amdgcn_mfma_f32_16x16x32_f16(pfrag, vfrag, oacc[nb], 0, 0, 0);
            }
        }
        __builtin_amdgcn_s_setprio(0);
    }

    // epilogue: normalize, write f16 [B,S,D]
#pragma unroll
    for (int r = 0; r < 4; r++) {
        float inv = 1.f / l_run[r];
        int s = i0 + w * 16 + quad * 4 + r;
#pragma unroll
        for (int nb = 0; nb < 4; nb++)
            Og[((size_t)b * SS + s) * DD + h * DHH + nb * 16 + lm] =
                (_Float16)(oacc[nb][r] * inv);
    }
}

extern "C" void kernel_launch(void* const* d_in, const int* in_sizes, int n_in,
                              void* d_out, int out_size, void* d_ws, size_t ws_size,
                              hipStream_t stream)
{
    const float* query = (const float*)d_in[0];
    const float* key   = (const float*)d_in[1];
    const float* value = (const float*)d_in[2];
    const int*   mask  = (const int*)d_in[3];
    const float* pe    = (const float*)d_in[4];
    const float* Wq    = (const float*)d_in[5];
    const float* Wk    = (const float*)d_in[6];
    const float* Wv    = (const float*)d_in[7];
    const float* Wo    = (const float*)d_in[8];
    float* out = (float*)d_out;

    _Float16* ws16 = (_Float16*)d_ws;
    const size_t MEG = 1048576;
    _Float16* wqf = ws16;
    _Float16* wkf = ws16 + 1 * MEG;
    _Float16* wvf = ws16 + 2 * MEG;
    _Float16* wof = ws16 + 3 * MEG;
    _Float16* pef = ws16 + 4 * MEG;
    _Float16* qp  = ws16 + 5 * MEG;     // [B,H,S,DH]
    _Float16* kp  = ws16 + 9 * MEG;     // [B,H,S,DH]
    _Float16* vp  = ws16 + 13 * MEG;    // [B,H,S,DH]
    _Float16* ao  = ws16 + 17 * MEG;    // [B,S,D]

    convert_kernel<<<5120, 256, 0, stream>>>(Wq, Wk, Wv, Wo, pe, ws16);

    gemm_proj<<<dim3(DD / 64, (BB * SS) / 128, 3), 256, 0, stream>>>(
        query, key, value, wqf, wkf, wvf, qp, kp, vp);

    attn_mfma<<<dim3(SS / 64, BB * HH), 256, 0, stream>>>(qp, kp, vp, mask, pef, ao);

    gemm_out<<<dim3(DD / 64, (BB * SS) / 128), 256, 0, stream>>>(ao, wof, out);
}

// Round 3
// 293.822 us; speedup vs baseline: 1.1188x; 1.0436x over previous
//
#include <hip/hip_runtime.h>
#include <math.h>

#define BB 4
#define SS 1024
#define DD 1024
#define HH 16
#define DHH 64

typedef _Float16 half8 __attribute__((ext_vector_type(8)));
typedef _Float16 half4v __attribute__((ext_vector_type(4)));
typedef float v4f __attribute__((ext_vector_type(4)));
typedef unsigned int u32;
typedef unsigned short u16;

// async global->LDS, 16B/lane. LDS dest is wave-uniform base + lane*16.
__device__ __forceinline__ void gload_lds16(const void* g, void* l) {
    __builtin_amdgcn_global_load_lds(
        (const __attribute__((address_space(1))) u32*)(const u32*)g,
        (__attribute__((address_space(3))) u32*)(u32*)l, 16, 0, 0);
}

// ---------------------------------------------------------------------------
// convert (small-ws fallback): W_q, W_k(*0.125), W_v, W_o, pe(*8)  (verified)
// ---------------------------------------------------------------------------
__global__ __launch_bounds__(256) void convert_kernel(
    const float* __restrict__ wq, const float* __restrict__ wk,
    const float* __restrict__ wv, const float* __restrict__ wo,
    const float* __restrict__ pe, _Float16* __restrict__ dst)
{
    const int i4 = blockIdx.x * 256 + threadIdx.x;
    const int region = i4 >> 18;
    const int local4 = i4 & 262143;
    const float* srcs[5] = {wq, wk, wv, wo, pe};
    const float scales[5] = {1.0f, 0.125f, 1.0f, 1.0f, 8.0f};
    const float sc = scales[region];
    float4 v = *(const float4*)(srcs[region] + (size_t)local4 * 4);
    half4v h = {(_Float16)(v.x * sc), (_Float16)(v.y * sc),
                (_Float16)(v.z * sc), (_Float16)(v.w * sc)};
    *(half4v*)(dst + ((size_t)region << 20) + (size_t)local4 * 4) = h;
}

// ---------------------------------------------------------------------------
// convert2 (big-ws): regions 0-4 as above; 5-8 query, 9-12 key, 13-16 value
// (fp32 -> f16, scale 1).  Region is block-uniform (1024 blocks/region).
// ---------------------------------------------------------------------------
__global__ __launch_bounds__(256) void convert2_kernel(
    const float* __restrict__ wq, const float* __restrict__ wk,
    const float* __restrict__ wv, const float* __restrict__ wo,
    const float* __restrict__ pe, const float* __restrict__ q,
    const float* __restrict__ k, const float* __restrict__ vv,
    _Float16* __restrict__ dst)
{
    const int i4 = blockIdx.x * 256 + threadIdx.x;
    const int region = i4 >> 18;
    const int local4 = i4 & 262143;
    const float* src;
    float sc = 1.0f;
    if (region == 0)      { src = wq; }
    else if (region == 1) { src = wk; sc = 0.125f; }
    else if (region == 2) { src = wv; }
    else if (region == 3) { src = wo; }
    else if (region == 4) { src = pe; sc = 8.0f; }
    else if (region < 9)  { src = q  + ((size_t)(region - 5)  << 20); }
    else if (region < 13) { src = k  + ((size_t)(region - 9)  << 20); }
    else                  { src = vv + ((size_t)(region - 13) << 20); }
    float4 v = *(const float4*)(src + (size_t)local4 * 4);
    half4v h = {(_Float16)(v.x * sc), (_Float16)(v.y * sc),
                (_Float16)(v.z * sc), (_Float16)(v.w * sc)};
    *(half4v*)(dst + ((size_t)region << 20) + (size_t)local4 * 4) = h;
}

// ---------------------------------------------------------------------------
// Fused Q/K/V projection, fp32-A path (R5-VERIFIED; small-ws fallback)
// ---------------------------------------------------------------------------
__global__ __launch_bounds__(256) void gemm_proj_f32(
    const float* __restrict__ Aq, const float* __restrict__ Ak,
    const float* __restrict__ Av,
    const _Float16* __restrict__ Wqf, const _Float16* __restrict__ Wkf,
    const _Float16* __restrict__ Wvf,
    _Float16* __restrict__ Cq, _Float16* __restrict__ Ck,
    _Float16* __restrict__ Cv)
{
    __shared__ _Float16 As[128 * 32];
    __shared__ _Float16 Bs[64 * 32];

    const int z = blockIdx.z;
    const float* A = z == 0 ? Aq : z == 1 ? Ak : Av;
    const _Float16* W = z == 0 ? Wqf : z == 1 ? Wkf : Wvf;
    _Float16* C = z == 0 ? Cq : z == 1 ? Ck : Cv;

    const int tid = threadIdx.x;
    const int w = tid >> 6, lane = tid & 63, lm = lane & 15, quad = lane >> 4;
    const int n0 = blockIdx.x * 64, m0 = blockIdx.y * 128;

    const int brow = tid >> 2, blc = (tid & 3) ^ (brow & 3);

    v4f zero4 = {0.f, 0.f, 0.f, 0.f};
    v4f acc[2][4];
#pragma unroll
    for (int mi = 0; mi < 2; mi++)
#pragma unroll
        for (int ni = 0; ni < 4; ni++) acc[mi][ni] = zero4;

    for (int k0 = 0; k0 < DD; k0 += 32) {
        __syncthreads();
        gload_lds16(W + (size_t)(n0 + brow) * DD + k0 + blc * 8, Bs + tid * 8);
#pragma unroll
        for (int u = 0; u < 4; u++) {
            int c4 = tid + 256 * u;
            int row = c4 >> 3, k4 = c4 & 7;
            float4 v = *(const float4*)(A + (size_t)(m0 + row) * DD + k0 + k4 * 4);
            half4v hv = {(_Float16)v.x, (_Float16)v.y, (_Float16)v.z, (_Float16)v.w};
            int c16 = k4 >> 1, hlf = k4 & 1;
            *(half4v*)(As + row * 32 + (((c16 ^ (row & 3)) << 3) + (hlf << 2))) = hv;
        }
        __syncthreads();

        half8 af[2], bf[4];
#pragma unroll
        for (int mi = 0; mi < 2; mi++) {
            int row = w * 32 + mi * 16 + lm;
            af[mi] = *(const half8*)(As + row * 32 + ((quad ^ (row & 3)) << 3));
        }
#pragma unroll
        for (int ni = 0; ni < 4; ni++) {
            int row = ni * 16 + lm;
            bf[ni] = *(const half8*)(Bs + row * 32 + ((quad ^ (row & 3)) << 3));
        }
#pragma unroll
        for (int mi = 0; mi < 2; mi++)
#pragma unroll
            for (int ni = 0; ni < 4; ni++)
                acc[mi][ni] = __builtin_amdgcn_mfma_f32_16x16x32_f16(
                    af[mi], bf[ni], acc[mi][ni], 0, 0, 0);
    }

    const int h = n0 >> 6;
#pragma unroll
    for (int mi = 0; mi < 2; mi++)
#pragma unroll
        for (int r = 0; r < 4; r++) {
            int m = m0 + w * 32 + mi * 16 + quad * 4 + r;
            int b = m >> 10, s = m & 1023;
            size_t base = ((size_t)(b * HH + h) * SS + s) * DHH;
#pragma unroll
            for (int ni = 0; ni < 4; ni++)
                C[base + ni * 16 + lm] = (_Float16)acc[mi][ni][r];
        }
}

// ---------------------------------------------------------------------------
// Fused Q/K/V projection, f16-A path (big-ws): A-staging is gemm_out's
// verified gload_lds16 pattern verbatim; B-staging/fragments/epilogue are
// gemm_proj_f32 verbatim.  Numerically identical to f32 path (same f32->f16
// rounding, performed in convert2 instead of in staging).
// ---------------------------------------------------------------------------
__global__ __launch_bounds__(256) void gemm_proj_f16(
    const _Float16* __restrict__ Aq, const _Float16* __restrict__ Ak,
    const _Float16* __restrict__ Av,
    const _Float16* __restrict__ Wqf, const _Float16* __restrict__ Wkf,
    const _Float16* __restrict__ Wvf,
    _Float16* __restrict__ Cq, _Float16* __restrict__ Ck,
    _Float16* __restrict__ Cv)
{
    __shared__ _Float16 As[128 * 32];
    __shared__ _Float16 Bs[64 * 32];

    const int z = blockIdx.z;
    const _Float16* A = z == 0 ? Aq : z == 1 ? Ak : Av;
    const _Float16* W = z == 0 ? Wqf : z == 1 ? Wkf : Wvf;
    _Float16* C = z == 0 ? Cq : z == 1 ? Ck : Cv;

    const int tid = threadIdx.x;
    const int w = tid >> 6, lane = tid & 63, lm = lane & 15, quad = lane >> 4;
    const int n0 = blockIdx.x * 64, m0 = blockIdx.y * 128;
    const int brow = tid >> 2, blc = (tid & 3) ^ (brow & 3);

    v4f zero4 = {0.f, 0.f, 0.f, 0.f};
    v4f acc[2][4];
#pragma unroll
    for (int mi = 0; mi < 2; mi++)
#pragma unroll
        for (int ni = 0; ni < 4; ni++) acc[mi][ni] = zero4;

    for (int k0 = 0; k0 < DD; k0 += 32) {
        __syncthreads();
        gload_lds16(W + (size_t)(n0 + brow) * DD + k0 + blc * 8, Bs + tid * 8);
#pragma unroll
        for (int u = 0; u < 2; u++) {
            int p = tid + 256 * u;
            int row = p >> 2, lc = (p & 3) ^ (row & 3);
            gload_lds16(A + (size_t)(m0 + row) * DD + k0 + lc * 8, As + p * 8);
        }
        __syncthreads();

        half8 af[2], bf[4];
#pragma unroll
        for (int mi = 0; mi < 2; mi++) {
            int row = w * 32 + mi * 16 + lm;
            af[mi] = *(const half8*)(As + row * 32 + ((quad ^ (row & 3)) << 3));
        }
#pragma unroll
        for (int ni = 0; ni < 4; ni++) {
            int row = ni * 16 + lm;
            bf[ni] = *(const half8*)(Bs + row * 32 + ((quad ^ (row & 3)) << 3));
        }
#pragma unroll
        for (int mi = 0; mi < 2; mi++)
#pragma unroll
            for (int ni = 0; ni < 4; ni++)
                acc[mi][ni] = __builtin_amdgcn_mfma_f32_16x16x32_f16(
                    af[mi], bf[ni], acc[mi][ni], 0, 0, 0);
    }

    const int h = n0 >> 6;
#pragma unroll
    for (int mi = 0; mi < 2; mi++)
#pragma unroll
        for (int r = 0; r < 4; r++) {
            int m = m0 + w * 32 + mi * 16 + quad * 4 + r;
            int b = m >> 10, s = m & 1023;
            size_t base = ((size_t)(b * HH + h) * SS + s) * DHH;
#pragma unroll
            for (int ni = 0; ni < 4; ni++)
                C[base + ni * 16 + lm] = (_Float16)acc[mi][ni][r];
        }
}

// ---------------------------------------------------------------------------
// Output GEMM: C(fp32 4096x1024) = A(f16) * W^T.  (R5-VERIFIED; unchanged)
// ---------------------------------------------------------------------------
__global__ __launch_bounds__(256) void gemm_out(
    const _Float16* __restrict__ A, const _Float16* __restrict__ W,
    float* __restrict__ C)
{
    __shared__ _Float16 As[128 * 32];
    __shared__ _Float16 Bs[64 * 32];

    const int tid = threadIdx.x;
    const int w = tid >> 6, lane = tid & 63, lm = lane & 15, quad = lane >> 4;
    const int n0 = blockIdx.x * 64, m0 = blockIdx.y * 128;
    const int brow = tid >> 2, blc = (tid & 3) ^ (brow & 3);

    v4f zero4 = {0.f, 0.f, 0.f, 0.f};
    v4f acc[2][4];
#pragma unroll
    for (int mi = 0; mi < 2; mi++)
#pragma unroll
        for (int ni = 0; ni < 4; ni++) acc[mi][ni] = zero4;

    for (int k0 = 0; k0 < DD; k0 += 32) {
        __syncthreads();
        gload_lds16(W + (size_t)(n0 + brow) * DD + k0 + blc * 8, Bs + tid * 8);
#pragma unroll
        for (int u = 0; u < 2; u++) {
            int p = tid + 256 * u;
            int row = p >> 2, lc = (p & 3) ^ (row & 3);
            gload_lds16(A + (size_t)(m0 + row) * DD + k0 + lc * 8, As + p * 8);
        }
        __syncthreads();

        half8 af[2], bf[4];
#pragma unroll
    for (int mi = 0; mi < 2; mi++) {
            int row = w * 32 + mi * 16 + lm;
            af[mi] = *(const half8*)(As + row * 32 + ((quad ^ (row & 3)) << 3));
        }
#pragma unroll
        for (int ni = 0; ni < 4; ni++) {
            int row = ni * 16 + lm;
            bf[ni] = *(const half8*)(Bs + row * 32 + ((quad ^ (row & 3)) << 3));
        }
#pragma unroll
        for (int mi = 0; mi < 2; mi++)
#pragma unroll
            for (int ni = 0; ni < 4; ni++)
                acc[mi][ni] = __builtin_amdgcn_mfma_f32_16x16x32_f16(
                    af[mi], bf[ni], acc[mi][ni], 0, 0, 0);
    }

#pragma unroll
    for (int mi = 0; mi < 2; mi++)
#pragma unroll
        for (int r = 0; r < 4; r++) {
            size_t base = (size_t)(m0 + w * 32 + mi * 16 + quad * 4 + r) * DD
                        + n0 + lm;
#pragma unroll
            for (int ni = 0; ni < 4; ni++)
                C[base + ni * 16] = acc[mi][ni][r];
        }
}

// ---------------------------------------------------------------------------
// MFMA flash attention — R9: LDS 45 KB -> 40 KB (all buffers stride 72 -> 64
// with XOR swizzles) so 4 blocks fit per CU (4 x 40960 = 160 KiB exactly);
// grid is exactly 4 blocks/CU so every block is resident (no drain round).
// Unified swizzle addr(row,c) = row*64 + (c ^ ((row&7)<<3)) for Ks/PEb/Pb
// (b128-safe: XOR touches bits >=3 only); Vt keeps its d>>3 col-XOR.
// Bank math per access verified: all b128 reads/writes at min 8 words/bank;
// Vt scalar writes 2-way; Pb scalar writes ~4-way (0.01% of cycles, accepted).
// Everything else is R8 verbatim (reg prefetch, setprio, 2 barriers/iter).
// ---------------------------------------------------------------------------
__global__ __launch_bounds__(256) void attn_mfma(
    const _Float16* __restrict__ Qg, const _Float16* __restrict__ Kg,
    const _Float16* __restrict__ Vg, const int* __restrict__ mask,
    const _Float16* __restrict__ peg, _Float16* __restrict__ Og)
{
    __shared__ _Float16 Ks[64 * 64];        // 8 KB  swizzled
    __shared__ _Float16 Vt[64 * 64];        // 8 KB  [d][j^swz]
    __shared__ _Float16 PEb[128 * 64];      // 16 KB swizzled
    __shared__ _Float16 Pb[4][16 * 64];     // 8 KB  per-wave P, swizzled

    const int tid = threadIdx.x;
    const int w = tid >> 6, lane = tid & 63;
    const int lm = lane & 15, quad = lane >> 4;
    const int it = blockIdx.x, i0 = it * 64;
    const int bh = blockIdx.y, b = bh >> 4, h = bh & 15;

    const _Float16* Qb = Qg + (size_t)bh * SS * DHH;
    const _Float16* Kb = Kg + (size_t)bh * SS * DHH;
    const _Float16* Vb = Vg + (size_t)bh * SS * DHH;
    const _Float16* peh = peg + (size_t)h * SS * DHH;

    float mi_f[4];
#pragma unroll
    for (int r = 0; r < 4; r++)
        mi_f[r] = (float)mask[b * SS + i0 + w * 16 + quad * 4 + r];

    // loop-invariant Q fragments, straight from global (L2-resident)
    half8 qf[2];
#pragma unroll
    for (int kc = 0; kc < 2; kc++)
        qf[kc] = *(const half8*)(Qb + (size_t)(i0 + w * 16 + lm) * DHH
                                 + kc * 32 + quad * 8);

    // per-thread staging indices
    const int srow = tid >> 3, sk8 = tid & 7;
    const int lmx = (lm & 7) << 3;          // read-side XOR for Ks/PEb/Pb

    v4f zero4 = {0.f, 0.f, 0.f, 0.f};
    float m_run[4], l_run[4];
    v4f oacc[4];
#pragma unroll
    for (int r = 0; r < 4; r++) { m_run[r] = -1e30f; l_run[r] = 0.f; }
#pragma unroll
    for (int nb = 0; nb < 4; nb++) oacc[nb] = zero4;

    // ---- prologue prefetch for jt = 0
    half8 kreg[2], vreg[2], pereg[4];
#pragma unroll
    for (int u = 0; u < 2; u++) {
        int row = srow + 32 * u;
        kreg[u] = *(const half8*)(Kb + (size_t)row * DHH + sk8 * 8);
        vreg[u] = *(const half8*)(Vb + (size_t)row * DHH + sk8 * 8);
    }
    {
        const int g0 = SS - 1 - i0 - 63;               // jt = 0
#pragma unroll
        for (int u = 0; u < 4; u++) {
            int o = srow + 32 * u;
            int g = g0 + o;
            half8 v = {0, 0, 0, 0, 0, 0, 0, 0};
            if (g < SS) v = *(const half8*)(peh + (size_t)g * DHH + sk8 * 8);
            pereg[u] = v;
        }
    }

    for (int jt = 0; jt < SS / 64; jt++) {
        const int j0 = jt * 64;
        const bool do_pe = (jt <= it);
        __syncthreads();                                   // (a) prev-iter reads done

        // ---- commit prefetched regs to LDS (vmcnt wait lands here)
#pragma unroll
        for (int u = 0; u < 2; u++) {
            int row = srow + 32 * u;
            *(half8*)(Ks + row * 64 + ((sk8 * 8) ^ ((row & 7) << 3))) = kreg[u];
        }
#pragma unroll
        for (int u = 0; u < 2; u++) {
            int row = srow + 32 * u;
            int jsw = row ^ (sk8 << 3);                    // Vt col-XOR
#pragma unroll
            for (int e = 0; e < 8; e++) Vt[(sk8 * 8 + e) * 64 + jsw] = vreg[u][e];
        }
        if (do_pe) {
#pragma unroll
            for (int u = 0; u < 4; u++) {
                int o = srow + 32 * u;
                *(half8*)(PEb + o * 64 + ((sk8 * 8) ^ ((o & 7) << 3))) = pereg[u];
            }
        }
        float mj_f[4];
#pragma unroll
        for (int nb = 0; nb < 4; nb++)
            mj_f[nb] = (float)mask[b * SS + j0 + nb * 16 + lm];
        __syncthreads();                                   // (b) staging visible

        // ---- prefetch tile jt+1 into regs (latency hidden under compute)
        if (jt + 1 < SS / 64) {
            const int j0n = j0 + 64;
#pragma unroll
            for (int u = 0; u < 2; u++) {
                int row = srow + 32 * u;
                kreg[u] = *(const half8*)(Kb + (size_t)(j0n + row) * DHH + sk8 * 8);
                vreg[u] = *(const half8*)(Vb + (size_t)(j0n + row) * DHH + sk8 * 8);
            }
            if (jt + 1 <= it) {
                const int g0n = SS - 1 + j0n - i0 - 63;
#pragma unroll
                for (int u = 0; u < 4; u++) {
                    int o = srow + 32 * u;
                    int g = g0n + o;
                    half8 v = {0, 0, 0, 0, 0, 0, 0, 0};
                    if (g < SS) v = *(const half8*)(peh + (size_t)g * DHH + sk8 * 8);
                    pereg[u] = v;
                }
            }
        }

        // ---- QK^T
        v4f sacc[4];
#pragma unroll
        for (int nb = 0; nb < 4; nb++) sacc[nb] = zero4;
        __builtin_amdgcn_s_setprio(1);
#pragma unroll
        for (int nb = 0; nb < 4; nb++)
#pragma unroll
            for (int kc = 0; kc < 2; kc++) {
                half8 kf = *(const half8*)(Ks + (nb * 16 + lm) * 64
                                           + ((kc * 32 + quad * 8) ^ lmx));
                sacc[nb] = __builtin_amdgcn_mfma_f32_16x16x32_f16(qf[kc], kf, sacc[nb], 0, 0, 0);
            }
        __builtin_amdgcn_s_setprio(0);

        // ---- relative position band: 5 tiles + shfl gather
        if (do_pe) {
            v4f racc[5];
#pragma unroll
            for (int e = 0; e < 5; e++) racc[e] = zero4;
            __builtin_amdgcn_s_setprio(1);
#pragma unroll
            for (int e = 0; e < 5; e++) {
                int row = (e + 3 - w) * 16 + lm;
#pragma unroll
                for (int kc = 0; kc < 2; kc++) {
                    half8 pf = *(const half8*)(PEb + row * 64
                                               + ((kc * 32 + quad * 8) ^ lmx));
                    racc[e] = __builtin_amdgcn_mfma_f32_16x16x32_f16(qf[kc], pf, racc[e], 0, 0, 0);
                }
            }
            __builtin_amdgcn_s_setprio(0);
#pragma unroll
            for (int nb = 0; nb < 4; nb++)
#pragma unroll
                for (int r = 0; r < 4; r++) {
                    int qr = quad * 4 + r;
                    float vsrc = (((lm + qr + 1) & 15) <= qr)
                               ? racc[nb][r] : racc[nb + 1][r];
                    int src = (lane & 48) | ((lm - qr - 1) & 15);
                    sacc[nb][r] += __shfl(vsrc, src);
                }
        }

        // ---- mask + online softmax
        float p[4][4];
        float alpha[4];
#pragma unroll
        for (int i = 0; i < 4; i++) {
            float mi = mi_f[i];
            float rmax = -1e30f;
#pragma unroll
            for (int j = 0; j < 4; j++) {
                float s = sacc[j][i];
                if (mi * mj_f[j] == 0.f) s = -1e9f;
                sacc[j][i] = s;
                rmax = fmaxf(rmax, s);
            }
#pragma unroll
            for (int off = 1; off < 16; off <<= 1)
                rmax = fmaxf(rmax, __shfl_xor(rmax, off));
            float mnew = fmaxf(m_run[i], rmax);
            alpha[i] = __expf(m_run[i] - mnew);
            m_run[i] = mnew;
            float rsum = 0.f;
#pragma unroll
            for (int j = 0; j < 4; j++) {
                p[j][i] = __expf(sacc[j][i] - mnew);
                rsum += p[j][i];
            }
#pragma unroll
            for (int off = 1; off < 16; off <<= 1)
                rsum += __shfl_xor(rsum, off);
            l_run[i] = l_run[i] * alpha[i] + rsum;
        }

        // write P (f16) into dedicated per-wave buffer; rescale O.
        // Pb[w] is written+read by wave w only (same-wave RAW via lgkmcnt).
        _Float16* Pw = &Pb[w][0];
#pragma unroll
        for (int nb = 0; nb < 4; nb++)
#pragma unroll
            for (int r = 0; r < 4; r++) {
                int qr = quad * 4 + r;
                Pw[qr * 64 + ((nb * 16 + lm) ^ ((qr & 7) << 3))] = (_Float16)p[nb][r];
            }
#pragma unroll
        for (int nb = 0; nb < 4; nb++)
#pragma unroll
            for (int r = 0; r < 4; r++) oacc[nb][r] *= alpha[r];

        // ---- PV
        __builtin_amdgcn_s_setprio(1);
#pragma unroll
        for (int kc = 0; kc < 2; kc++) {
            half8 pfrag = *(const half8*)(Pw + lm * 64 + ((kc * 32 + quad * 8) ^ lmx));
#pragma unroll
            for (int nb = 0; nb < 4; nb++) {
                int d = nb * 16 + lm;
                int col = (kc * 32 + quad * 8) ^ (((d >> 3) & 7) << 3);
                half8 vfrag = *(const half8*)(Vt + d * 64 + col);
                oacc[nb] = __builtin_amdgcn_mfma_f32_16x16x32_f16(pfrag, vfrag, oacc[nb], 0, 0, 0);
            }
        }
        __builtin_amdgcn_s_setprio(0);
    }

    // epilogue: normalize, write f16 [B,S,D]
#pragma unroll
    for (int r = 0; r < 4; r++) {
        float inv = 1.f / l_run[r];
        int s = i0 + w * 16 + quad * 4 + r;
#pragma unroll
        for (int nb = 0; nb < 4; nb++)
            Og[((size_t)b * SS + s) * DD + h * DHH + nb * 16 + lm] =
                (_Float16)(oacc[nb][r] * inv);
    }
}

extern "C" void kernel_launch(void* const* d_in, const int* in_sizes, int n_in,
                              void* d_out, int out_size, void* d_ws, size_t ws_size,
                              hipStream_t stream)
{
    const float* query = (const float*)d_in[0];
    const float* key   = (const float*)d_in[1];
    const float* value = (const float*)d_in[2];
    const int*   mask  = (const int*)d_in[3];
    const float* pe    = (const float*)d_in[4];
    const float* Wq    = (const float*)d_in[5];
    const float* Wk    = (const float*)d_in[6];
    const float* Wv    = (const float*)d_in[7];
    const float* Wo    = (const float*)d_in[8];
    float* out = (float*)d_out;

    _Float16* ws16 = (_Float16*)d_ws;
    const size_t MEG = 1048576;
    _Float16* wqf = ws16;
    _Float16* wkf = ws16 + 1 * MEG;
    _Float16* wvf = ws16 + 2 * MEG;
    _Float16* wof = ws16 + 3 * MEG;
    _Float16* pef = ws16 + 4 * MEG;

    const bool big = ws_size >= (size_t)33 * MEG * sizeof(_Float16);

    if (big) {
        // big-ws layout: q16/k16/v16 at 5/9/13; qp/kp/vp at 17/21/25; ao at 29
        _Float16* q16 = ws16 + 5 * MEG;
        _Float16* k16 = ws16 + 9 * MEG;
        _Float16* v16 = ws16 + 13 * MEG;
        _Float16* qp  = ws16 + 17 * MEG;
        _Float16* kp  = ws16 + 21 * MEG;
        _Float16* vp  = ws16 + 25 * MEG;
        _Float16* ao  = ws16 + 29 * MEG;

        convert2_kernel<<<17408, 256, 0, stream>>>(
            Wq, Wk, Wv, Wo, pe, query, key, value, ws16);

        gemm_proj_f16<<<dim3(DD / 64, (BB * SS) / 128, 3), 256, 0, stream>>>(
            q16, k16, v16, wqf, wkf, wvf, qp, kp, vp);

        attn_mfma<<<dim3(SS / 64, BB * HH), 256, 0, stream>>>(
            qp, kp, vp, mask, pef, ao);

        gemm_out<<<dim3(DD / 64, (BB * SS) / 128), 256, 0, stream>>>(ao, wof, out);
    } else {
        // fallback: original verified layout/path
        _Float16* qp  = ws16 + 5 * MEG;
        _Float16* kp  = ws16 + 9 * MEG;
        _Float16* vp  = ws16 + 13 * MEG;
        _Float16* ao  = ws16 + 17 * MEG;

        convert_kernel<<<5120, 256, 0, stream>>>(Wq, Wk, Wv, Wo, pe, ws16);

        gemm_proj_f32<<<dim3(DD / 64, (BB * SS) / 128, 3), 256, 0, stream>>>(
            query, key, value, wqf, wkf, wvf, qp, kp, vp);

        attn_mfma<<<dim3(SS / 64, BB * HH), 256, 0, stream>>>(
            qp, kp, vp, mask, pef, ao);

        gemm_out<<<dim3(DD / 64, (BB * SS) / 128), 256, 0, stream>>>(ao, wof, out);
    }
}

// Round 4
// 282.359 us; speedup vs baseline: 1.1642x; 1.0406x over previous
//
#include <hip/hip_runtime.h>
#include <math.h>

#define BB 4
#define SS 1024
#define DD 1024
#define HH 16
#define DHH 64

typedef _Float16 half8 __attribute__((ext_vector_type(8)));
typedef _Float16 half4v __attribute__((ext_vector_type(4)));
typedef float v4f __attribute__((ext_vector_type(4)));
typedef unsigned int u32;
typedef unsigned short u16;

// async global->LDS, 16B/lane. LDS dest is wave-uniform base + lane*16.
__device__ __forceinline__ void gload_lds16(const void* g, void* l) {
    __builtin_amdgcn_global_load_lds(
        (const __attribute__((address_space(1))) u32*)(const u32*)g,
        (__attribute__((address_space(3))) u32*)(u32*)l, 16, 0, 0);
}

// ---------------------------------------------------------------------------
// convert (small-ws fallback): W_q, W_k(*0.125), W_v, W_o, pe(*8)  (verified)
// ---------------------------------------------------------------------------
__global__ __launch_bounds__(256) void convert_kernel(
    const float* __restrict__ wq, const float* __restrict__ wk,
    const float* __restrict__ wv, const float* __restrict__ wo,
    const float* __restrict__ pe, _Float16* __restrict__ dst)
{
    const int i4 = blockIdx.x * 256 + threadIdx.x;
    const int region = i4 >> 18;
    const int local4 = i4 & 262143;
    const float* srcs[5] = {wq, wk, wv, wo, pe};
    const float scales[5] = {1.0f, 0.125f, 1.0f, 1.0f, 8.0f};
    const float sc = scales[region];
    float4 v = *(const float4*)(srcs[region] + (size_t)local4 * 4);
    half4v h = {(_Float16)(v.x * sc), (_Float16)(v.y * sc),
                (_Float16)(v.z * sc), (_Float16)(v.w * sc)};
    *(half4v*)(dst + ((size_t)region << 20) + (size_t)local4 * 4) = h;
}

// ---------------------------------------------------------------------------
// convert2 (big-ws): regions 0-4 as above; 5-8 query, 9-12 key, 13-16 value
// (fp32 -> f16, scale 1).  Region is block-uniform (1024 blocks/region).
// ---------------------------------------------------------------------------
__global__ __launch_bounds__(256) void convert2_kernel(
    const float* __restrict__ wq, const float* __restrict__ wk,
    const float* __restrict__ wv, const float* __restrict__ wo,
    const float* __restrict__ pe, const float* __restrict__ q,
    const float* __restrict__ k, const float* __restrict__ vv,
    _Float16* __restrict__ dst)
{
    const int i4 = blockIdx.x * 256 + threadIdx.x;
    const int region = i4 >> 18;
    const int local4 = i4 & 262143;
    const float* src;
    float sc = 1.0f;
    if (region == 0)      { src = wq; }
    else if (region == 1) { src = wk; sc = 0.125f; }
    else if (region == 2) { src = wv; }
    else if (region == 3) { src = wo; }
    else if (region == 4) { src = pe; sc = 8.0f; }
    else if (region < 9)  { src = q  + ((size_t)(region - 5)  << 20); }
    else if (region < 13) { src = k  + ((size_t)(region - 9)  << 20); }
    else                  { src = vv + ((size_t)(region - 13) << 20); }
    float4 v = *(const float4*)(src + (size_t)local4 * 4);
    half4v h = {(_Float16)(v.x * sc), (_Float16)(v.y * sc),
                (_Float16)(v.z * sc), (_Float16)(v.w * sc)};
    *(half4v*)(dst + ((size_t)region << 20) + (size_t)local4 * 4) = h;
}

// ---------------------------------------------------------------------------
// Fused Q/K/V projection, fp32-A path (R5-VERIFIED; small-ws fallback)
// ---------------------------------------------------------------------------
__global__ __launch_bounds__(256) void gemm_proj_f32(
    const float* __restrict__ Aq, const float* __restrict__ Ak,
    const float* __restrict__ Av,
    const _Float16* __restrict__ Wqf, const _Float16* __restrict__ Wkf,
    const _Float16* __restrict__ Wvf,
    _Float16* __restrict__ Cq, _Float16* __restrict__ Ck,
    _Float16* __restrict__ Cv)
{
    __shared__ _Float16 As[128 * 32];
    __shared__ _Float16 Bs[64 * 32];

    const int z = blockIdx.z;
    const float* A = z == 0 ? Aq : z == 1 ? Ak : Av;
    const _Float16* W = z == 0 ? Wqf : z == 1 ? Wkf : Wvf;
    _Float16* C = z == 0 ? Cq : z == 1 ? Ck : Cv;

    const int tid = threadIdx.x;
    const int w = tid >> 6, lane = tid & 63, lm = lane & 15, quad = lane >> 4;
    const int n0 = blockIdx.x * 64, m0 = blockIdx.y * 128;

    const int brow = tid >> 2, blc = (tid & 3) ^ (brow & 3);

    v4f zero4 = {0.f, 0.f, 0.f, 0.f};
    v4f acc[2][4];
#pragma unroll
    for (int mi = 0; mi < 2; mi++)
#pragma unroll
        for (int ni = 0; ni < 4; ni++) acc[mi][ni] = zero4;

    for (int k0 = 0; k0 < DD; k0 += 32) {
        __syncthreads();
        gload_lds16(W + (size_t)(n0 + brow) * DD + k0 + blc * 8, Bs + tid * 8);
#pragma unroll
        for (int u = 0; u < 4; u++) {
            int c4 = tid + 256 * u;
            int row = c4 >> 3, k4 = c4 & 7;
            float4 v = *(const float4*)(A + (size_t)(m0 + row) * DD + k0 + k4 * 4);
            half4v hv = {(_Float16)v.x, (_Float16)v.y, (_Float16)v.z, (_Float16)v.w};
            int c16 = k4 >> 1, hlf = k4 & 1;
            *(half4v*)(As + row * 32 + (((c16 ^ (row & 3)) << 3) + (hlf << 2))) = hv;
        }
        __syncthreads();

        half8 af[2], bf[4];
#pragma unroll
        for (int mi = 0; mi < 2; mi++) {
            int row = w * 32 + mi * 16 + lm;
            af[mi] = *(const half8*)(As + row * 32 + ((quad ^ (row & 3)) << 3));
        }
#pragma unroll
        for (int ni = 0; ni < 4; ni++) {
            int row = ni * 16 + lm;
            bf[ni] = *(const half8*)(Bs + row * 32 + ((quad ^ (row & 3)) << 3));
        }
#pragma unroll
        for (int mi = 0; mi < 2; mi++)
#pragma unroll
            for (int ni = 0; ni < 4; ni++)
                acc[mi][ni] = __builtin_amdgcn_mfma_f32_16x16x32_f16(
                    af[mi], bf[ni], acc[mi][ni], 0, 0, 0);
    }

    const int h = n0 >> 6;
#pragma unroll
    for (int mi = 0; mi < 2; mi++)
#pragma unroll
        for (int r = 0; r < 4; r++) {
            int m = m0 + w * 32 + mi * 16 + quad * 4 + r;
            int b = m >> 10, s = m & 1023;
            size_t base = ((size_t)(b * HH + h) * SS + s) * DHH;
#pragma unroll
            for (int ni = 0; ni < 4; ni++)
                C[base + ni * 16 + lm] = (_Float16)acc[mi][ni][r];
        }
}

// ---------------------------------------------------------------------------
// Fused Q/K/V projection, f16-A path (big-ws; R3-VERIFIED)
// ---------------------------------------------------------------------------
__global__ __launch_bounds__(256) void gemm_proj_f16(
    const _Float16* __restrict__ Aq, const _Float16* __restrict__ Ak,
    const _Float16* __restrict__ Av,
    const _Float16* __restrict__ Wqf, const _Float16* __restrict__ Wkf,
    const _Float16* __restrict__ Wvf,
    _Float16* __restrict__ Cq, _Float16* __restrict__ Ck,
    _Float16* __restrict__ Cv)
{
    __shared__ _Float16 As[128 * 32];
    __shared__ _Float16 Bs[64 * 32];

    const int z = blockIdx.z;
    const _Float16* A = z == 0 ? Aq : z == 1 ? Ak : Av;
    const _Float16* W = z == 0 ? Wqf : z == 1 ? Wkf : Wvf;
    _Float16* C = z == 0 ? Cq : z == 1 ? Ck : Cv;

    const int tid = threadIdx.x;
    const int w = tid >> 6, lane = tid & 63, lm = lane & 15, quad = lane >> 4;
    const int n0 = blockIdx.x * 64, m0 = blockIdx.y * 128;
    const int brow = tid >> 2, blc = (tid & 3) ^ (brow & 3);

    v4f zero4 = {0.f, 0.f, 0.f, 0.f};
    v4f acc[2][4];
#pragma unroll
    for (int mi = 0; mi < 2; mi++)
#pragma unroll
        for (int ni = 0; ni < 4; ni++) acc[mi][ni] = zero4;

    for (int k0 = 0; k0 < DD; k0 += 32) {
        __syncthreads();
        gload_lds16(W + (size_t)(n0 + brow) * DD + k0 + blc * 8, Bs + tid * 8);
#pragma unroll
        for (int u = 0; u < 2; u++) {
            int p = tid + 256 * u;
            int row = p >> 2, lc = (p & 3) ^ (row & 3);
            gload_lds16(A + (size_t)(m0 + row) * DD + k0 + lc * 8, As + p * 8);
        }
        __syncthreads();

        half8 af[2], bf[4];
#pragma unroll
        for (int mi = 0; mi < 2; mi++) {
            int row = w * 32 + mi * 16 + lm;
            af[mi] = *(const half8*)(As + row * 32 + ((quad ^ (row & 3)) << 3));
        }
#pragma unroll
        for (int ni = 0; ni < 4; ni++) {
            int row = ni * 16 + lm;
            bf[ni] = *(const half8*)(Bs + row * 32 + ((quad ^ (row & 3)) << 3));
        }
#pragma unroll
        for (int mi = 0; mi < 2; mi++)
#pragma unroll
            for (int ni = 0; ni < 4; ni++)
                acc[mi][ni] = __builtin_amdgcn_mfma_f32_16x16x32_f16(
                    af[mi], bf[ni], acc[mi][ni], 0, 0, 0);
    }

    const int h = n0 >> 6;
#pragma unroll
    for (int mi = 0; mi < 2; mi++)
#pragma unroll
        for (int r = 0; r < 4; r++) {
            int m = m0 + w * 32 + mi * 16 + quad * 4 + r;
            int b = m >> 10, s = m & 1023;
            size_t base = ((size_t)(b * HH + h) * SS + s) * DHH;
#pragma unroll
            for (int ni = 0; ni < 4; ni++)
                C[base + ni * 16 + lm] = (_Float16)acc[mi][ni][r];
        }
}

// ---------------------------------------------------------------------------
// Output GEMM: C(fp32 4096x1024) = A(f16) * W^T.  (R5-VERIFIED; unchanged)
// ---------------------------------------------------------------------------
__global__ __launch_bounds__(256) void gemm_out(
    const _Float16* __restrict__ A, const _Float16* __restrict__ W,
    float* __restrict__ C)
{
    __shared__ _Float16 As[128 * 32];
    __shared__ _Float16 Bs[64 * 32];

    const int tid = threadIdx.x;
    const int w = tid >> 6, lane = tid & 63, lm = lane & 15, quad = lane >> 4;
    const int n0 = blockIdx.x * 64, m0 = blockIdx.y * 128;
    const int brow = tid >> 2, blc = (tid & 3) ^ (brow & 3);

    v4f zero4 = {0.f, 0.f, 0.f, 0.f};
    v4f acc[2][4];
#pragma unroll
    for (int mi = 0; mi < 2; mi++)
#pragma unroll
        for (int ni = 0; ni < 4; ni++) acc[mi][ni] = zero4;

    for (int k0 = 0; k0 < DD; k0 += 32) {
        __syncthreads();
        gload_lds16(W + (size_t)(n0 + brow) * DD + k0 + blc * 8, Bs + tid * 8);
#pragma unroll
        for (int u = 0; u < 2; u++) {
            int p = tid + 256 * u;
            int row = p >> 2, lc = (p & 3) ^ (row & 3);
            gload_lds16(A + (size_t)(m0 + row) * DD + k0 + lc * 8, As + p * 8);
        }
        __syncthreads();

        half8 af[2], bf[4];
#pragma unroll
    for (int mi = 0; mi < 2; mi++) {
            int row = w * 32 + mi * 16 + lm;
            af[mi] = *(const half8*)(As + row * 32 + ((quad ^ (row & 3)) << 3));
        }
#pragma unroll
        for (int ni = 0; ni < 4; ni++) {
            int row = ni * 16 + lm;
            bf[ni] = *(const half8*)(Bs + row * 32 + ((quad ^ (row & 3)) << 3));
        }
#pragma unroll
        for (int mi = 0; mi < 2; mi++)
#pragma unroll
            for (int ni = 0; ni < 4; ni++)
                acc[mi][ni] = __builtin_amdgcn_mfma_f32_16x16x32_f16(
                    af[mi], bf[ni], acc[mi][ni], 0, 0, 0);
    }

#pragma unroll
    for (int mi = 0; mi < 2; mi++)
#pragma unroll
        for (int r = 0; r < 4; r++) {
            size_t base = (size_t)(m0 + w * 32 + mi * 16 + quad * 4 + r) * DD
                        + n0 + lm;
#pragma unroll
            for (int ni = 0; ni < 4; ni++)
                C[base + ni * 16] = acc[mi][ni][r];
        }
}

// ---------------------------------------------------------------------------
// MFMA flash attention — R10: two changes on R9 (counters: dur 117us flat,
// Occ 17.7 flat, conflicts 6.3e6 flat -> R9's 4-blocks/CU theory was wrong;
// real limiter is CU load imbalance):
//  1) it/bh LOAD-BALANCE SWIZZLE.  Old grid mapping: co-resident blocks on a
//     CU are lid c, c+256, c+512, c+768; 256 % 16 == 0 so all four share the
//     same `it` -> CUs with it=15 blocks do 1.56x the MFMA of it=0 CUs
//     (per-block MFMA = 256 + 10*(it+1)).  Remap (bijective per bh):
//       it = ((lid&15) + 4*(lid>>8)) & 15, bh = lid>>4
//     -> co-resident its become {x, x+4, x+8, x+12}: near-uniform CU load
//     under round-robin dispatch (and still balanced under contiguous fill).
//  2) ROW-SUM VIA ONES-MFMA: the rsum 4x4-round __shfl_xor butterfly (16
//     LDS-pipe bpermutes/iter) is deleted; instead lacc accumulates
//     mfma(pfrag, ones, lacc) in the PV phase (pfrag already loaded; +2
//     MFMA/iter), rescaled by alpha exactly like oacc.  l now sums the
//     f16-rounded P (same values PV uses); epilogue takes inv from lacc.
// Everything else (reg prefetch, setprio, 2 barriers/iter, stride-64
// XOR-swizzled LDS) is R9 verbatim.
// ---------------------------------------------------------------------------
__global__ __launch_bounds__(256) void attn_mfma(
    const _Float16* __restrict__ Qg, const _Float16* __restrict__ Kg,
    const _Float16* __restrict__ Vg, const int* __restrict__ mask,
    const _Float16* __restrict__ peg, _Float16* __restrict__ Og)
{
    __shared__ _Float16 Ks[64 * 64];        // 8 KB  swizzled
    __shared__ _Float16 Vt[64 * 64];        // 8 KB  [d][j^swz]
    __shared__ _Float16 PEb[128 * 64];      // 16 KB swizzled
    __shared__ _Float16 Pb[4][16 * 64];     // 8 KB  per-wave P, swizzled

    const int tid = threadIdx.x;
    const int w = tid >> 6, lane = tid & 63;
    const int lm = lane & 15, quad = lane >> 4;

    // load-balance swizzle (bijective): co-resident blocks get spread its
    const int lid = blockIdx.y * 16 + blockIdx.x;
    const int it = ((lid & 15) + ((lid >> 8) << 2)) & 15;
    const int bh = lid >> 4;
    const int i0 = it * 64;
    const int b = bh >> 4, h = bh & 15;

    const _Float16* Qb = Qg + (size_t)bh * SS * DHH;
    const _Float16* Kb = Kg + (size_t)bh * SS * DHH;
    const _Float16* Vb = Vg + (size_t)bh * SS * DHH;
    const _Float16* peh = peg + (size_t)h * SS * DHH;

    float mi_f[4];
#pragma unroll
    for (int r = 0; r < 4; r++)
        mi_f[r] = (float)mask[b * SS + i0 + w * 16 + quad * 4 + r];

    // loop-invariant Q fragments, straight from global (L2-resident)
    half8 qf[2];
#pragma unroll
    for (int kc = 0; kc < 2; kc++)
        qf[kc] = *(const half8*)(Qb + (size_t)(i0 + w * 16 + lm) * DHH
                                 + kc * 32 + quad * 8);

    // per-thread staging indices
    const int srow = tid >> 3, sk8 = tid & 7;
    const int lmx = (lm & 7) << 3;          // read-side XOR for Ks/PEb/Pb

    // ones B-fragment for row-sum MFMA
    half8 ones8 = {(_Float16)1, (_Float16)1, (_Float16)1, (_Float16)1,
                   (_Float16)1, (_Float16)1, (_Float16)1, (_Float16)1};

    v4f zero4 = {0.f, 0.f, 0.f, 0.f};
    float m_run[4];
    v4f oacc[4], lacc;
#pragma unroll
    for (int r = 0; r < 4; r++) m_run[r] = -1e30f;
#pragma unroll
    for (int nb = 0; nb < 4; nb++) oacc[nb] = zero4;
    lacc = zero4;

    // ---- prologue prefetch for jt = 0
    half8 kreg[2], vreg[2], pereg[4];
#pragma unroll
    for (int u = 0; u < 2; u++) {
        int row = srow + 32 * u;
        kreg[u] = *(const half8*)(Kb + (size_t)row * DHH + sk8 * 8);
        vreg[u] = *(const half8*)(Vb + (size_t)row * DHH + sk8 * 8);
    }
    {
        const int g0 = SS - 1 - i0 - 63;               // jt = 0
#pragma unroll
        for (int u = 0; u < 4; u++) {
            int o = srow + 32 * u;
            int g = g0 + o;
            half8 v = {0, 0, 0, 0, 0, 0, 0, 0};
            if (g < SS) v = *(const half8*)(peh + (size_t)g * DHH + sk8 * 8);
            pereg[u] = v;
        }
    }

    for (int jt = 0; jt < SS / 64; jt++) {
        const int j0 = jt * 64;
        const bool do_pe = (jt <= it);
        __syncthreads();                                   // (a) prev-iter reads done

        // ---- commit prefetched regs to LDS (vmcnt wait lands here)
#pragma unroll
        for (int u = 0; u < 2; u++) {
            int row = srow + 32 * u;
            *(half8*)(Ks + row * 64 + ((sk8 * 8) ^ ((row & 7) << 3))) = kreg[u];
        }
#pragma unroll
        for (int u = 0; u < 2; u++) {
            int row = srow + 32 * u;
            int jsw = row ^ (sk8 << 3);                    // Vt col-XOR
#pragma unroll
            for (int e = 0; e < 8; e++) Vt[(sk8 * 8 + e) * 64 + jsw] = vreg[u][e];
        }
        if (do_pe) {
#pragma unroll
            for (int u = 0; u < 4; u++) {
                int o = srow + 32 * u;
                *(half8*)(PEb + o * 64 + ((sk8 * 8) ^ ((o & 7) << 3))) = pereg[u];
            }
        }
        float mj_f[4];
#pragma unroll
        for (int nb = 0; nb < 4; nb++)
            mj_f[nb] = (float)mask[b * SS + j0 + nb * 16 + lm];
        __syncthreads();                                   // (b) staging visible

        // ---- prefetch tile jt+1 into regs (latency hidden under compute)
        if (jt + 1 < SS / 64) {
            const int j0n = j0 + 64;
#pragma unroll
            for (int u = 0; u < 2; u++) {
                int row = srow + 32 * u;
                kreg[u] = *(const half8*)(Kb + (size_t)(j0n + row) * DHH + sk8 * 8);
                vreg[u] = *(const half8*)(Vb + (size_t)(j0n + row) * DHH + sk8 * 8);
            }
            if (jt + 1 <= it) {
                const int g0n = SS - 1 + j0n - i0 - 63;
#pragma unroll
                for (int u = 0; u < 4; u++) {
                    int o = srow + 32 * u;
                    int g = g0n + o;
                    half8 v = {0, 0, 0, 0, 0, 0, 0, 0};
                    if (g < SS) v = *(const half8*)(peh + (size_t)g * DHH + sk8 * 8);
                    pereg[u] = v;
                }
            }
        }

        // ---- QK^T
        v4f sacc[4];
#pragma unroll
        for (int nb = 0; nb < 4; nb++) sacc[nb] = zero4;
        __builtin_amdgcn_s_setprio(1);
#pragma unroll
        for (int nb = 0; nb < 4; nb++)
#pragma unroll
            for (int kc = 0; kc < 2; kc++) {
                half8 kf = *(const half8*)(Ks + (nb * 16 + lm) * 64
                                           + ((kc * 32 + quad * 8) ^ lmx));
                sacc[nb] = __builtin_amdgcn_mfma_f32_16x16x32_f16(qf[kc], kf, sacc[nb], 0, 0, 0);
            }
        __builtin_amdgcn_s_setprio(0);

        // ---- relative position band: 5 tiles + shfl gather
        if (do_pe) {
            v4f racc[5];
#pragma unroll
            for (int e = 0; e < 5; e++) racc[e] = zero4;
            __builtin_amdgcn_s_setprio(1);
#pragma unroll
            for (int e = 0; e < 5; e++) {
                int row = (e + 3 - w) * 16 + lm;
#pragma unroll
                for (int kc = 0; kc < 2; kc++) {
                    half8 pf = *(const half8*)(PEb + row * 64
                                               + ((kc * 32 + quad * 8) ^ lmx));
                    racc[e] = __builtin_amdgcn_mfma_f32_16x16x32_f16(qf[kc], pf, racc[e], 0, 0, 0);
                }
            }
            __builtin_amdgcn_s_setprio(0);
#pragma unroll
            for (int nb = 0; nb < 4; nb++)
#pragma unroll
                for (int r = 0; r < 4; r++) {
                    int qr = quad * 4 + r;
                    float vsrc = (((lm + qr + 1) & 15) <= qr)
                               ? racc[nb][r] : racc[nb + 1][r];
                    int src = (lane & 48) | ((lm - qr - 1) & 15);
                    sacc[nb][r] += __shfl(vsrc, src);
                }
        }

        // ---- mask + online softmax (rmax butterfly only; rsum via MFMA)
        float p[4][4];
        float alpha[4];
#pragma unroll
        for (int i = 0; i < 4; i++) {
            float mi = mi_f[i];
            float rmax = -1e30f;
#pragma unroll
            for (int j = 0; j < 4; j++) {
                float s = sacc[j][i];
                if (mi * mj_f[j] == 0.f) s = -1e9f;
                sacc[j][i] = s;
                rmax = fmaxf(rmax, s);
            }
#pragma unroll
            for (int off = 1; off < 16; off <<= 1)
                rmax = fmaxf(rmax, __shfl_xor(rmax, off));
            float mnew = fmaxf(m_run[i], rmax);
            alpha[i] = __expf(m_run[i] - mnew);
            m_run[i] = mnew;
#pragma unroll
            for (int j = 0; j < 4; j++)
                p[j][i] = __expf(sacc[j][i] - mnew);
        }

        // write P (f16) into dedicated per-wave buffer; rescale O and l.
        // Pb[w] is written+read by wave w only (same-wave RAW via lgkmcnt).
        _Float16* Pw = &Pb[w][0];
#pragma unroll
        for (int nb = 0; nb < 4; nb++)
#pragma unroll
            for (int r = 0; r < 4; r++) {
                int qr = quad * 4 + r;
                Pw[qr * 64 + ((nb * 16 + lm) ^ ((qr & 7) << 3))] = (_Float16)p[nb][r];
            }
#pragma unroll
        for (int nb = 0; nb < 4; nb++)
#pragma unroll
            for (int r = 0; r < 4; r++) oacc[nb][r] *= alpha[r];
#pragma unroll
        for (int r = 0; r < 4; r++) lacc[r] *= alpha[r];

        // ---- PV (+ row-sum MFMA into lacc; pfrag reused)
        __builtin_amdgcn_s_setprio(1);
#pragma unroll
        for (int kc = 0; kc < 2; kc++) {
            half8 pfrag = *(const half8*)(Pw + lm * 64 + ((kc * 32 + quad * 8) ^ lmx));
            lacc = __builtin_amdgcn_mfma_f32_16x16x32_f16(pfrag, ones8, lacc, 0, 0, 0);
#pragma unroll
            for (int nb = 0; nb < 4; nb++) {
                int d = nb * 16 + lm;
                int col = (kc * 32 + quad * 8) ^ (((d >> 3) & 7) << 3);
                half8 vfrag = *(const half8*)(Vt + d * 64 + col);
                oacc[nb] = __builtin_amdgcn_mfma_f32_16x16x32_f16(pfrag, vfrag, oacc[nb], 0, 0, 0);
            }
        }
        __builtin_amdgcn_s_setprio(0);
    }

    // epilogue: normalize, write f16 [B,S,D]
#pragma unroll
    for (int r = 0; r < 4; r++) {
        float inv = 1.f / lacc[r];
        int s = i0 + w * 16 + quad * 4 + r;
#pragma unroll
        for (int nb = 0; nb < 4; nb++)
            Og[((size_t)b * SS + s) * DD + h * DHH + nb * 16 + lm] =
                (_Float16)(oacc[nb][r] * inv);
    }
}

extern "C" void kernel_launch(void* const* d_in, const int* in_sizes, int n_in,
                              void* d_out, int out_size, void* d_ws, size_t ws_size,
                              hipStream_t stream)
{
    const float* query = (const float*)d_in[0];
    const float* key   = (const float*)d_in[1];
    const float* value = (const float*)d_in[2];
    const int*   mask  = (const int*)d_in[3];
    const float* pe    = (const float*)d_in[4];
    const float* Wq    = (const float*)d_in[5];
    const float* Wk    = (const float*)d_in[6];
    const float* Wv    = (const float*)d_in[7];
    const float* Wo    = (const float*)d_in[8];
    float* out = (float*)d_out;

    _Float16* ws16 = (_Float16*)d_ws;
    const size_t MEG = 1048576;
    _Float16* wqf = ws16;
    _Float16* wkf = ws16 + 1 * MEG;
    _Float16* wvf = ws16 + 2 * MEG;
    _Float16* wof = ws16 + 3 * MEG;
    _Float16* pef = ws16 + 4 * MEG;

    const bool big = ws_size >= (size_t)33 * MEG * sizeof(_Float16);

    if (big) {
        // big-ws layout: q16/k16/v16 at 5/9/13; qp/kp/vp at 17/21/25; ao at 29
        _Float16* q16 = ws16 + 5 * MEG;
        _Float16* k16 = ws16 + 9 * MEG;
        _Float16* v16 = ws16 + 13 * MEG;
        _Float16* qp  = ws16 + 17 * MEG;
        _Float16* kp  = ws16 + 21 * MEG;
        _Float16* vp  = ws16 + 25 * MEG;
        _Float16* ao  = ws16 + 29 * MEG;

        convert2_kernel<<<17408, 256, 0, stream>>>(
            Wq, Wk, Wv, Wo, pe, query, key, value, ws16);

        gemm_proj_f16<<<dim3(DD / 64, (BB * SS) / 128, 3), 256, 0, stream>>>(
            q16, k16, v16, wqf, wkf, wvf, qp, kp, vp);

        attn_mfma<<<dim3(SS / 64, BB * HH), 256, 0, stream>>>(
            qp, kp, vp, mask, pef, ao);

        gemm_out<<<dim3(DD / 64, (BB * SS) / 128), 256, 0, stream>>>(ao, wof, out);
    } else {
        // fallback: original verified layout/path
        _Float16* qp  = ws16 + 5 * MEG;
        _Float16* kp  = ws16 + 9 * MEG;
        _Float16* vp  = ws16 + 13 * MEG;
        _Float16* ao  = ws16 + 17 * MEG;

        convert_kernel<<<5120, 256, 0, stream>>>(Wq, Wk, Wv, Wo, pe, ws16);

        gemm_proj_f32<<<dim3(DD / 64, (BB * SS) / 128, 3), 256, 0, stream>>>(
            query, key, value, wqf, wkf, wvf, qp, kp, vp);

        attn_mfma<<<dim3(SS / 64, BB * HH), 256, 0, stream>>>(
            qp, kp, vp, mask, pef, ao);

        gemm_out<<<dim3(DD / 64, (BB * SS) / 128), 256, 0, stream>>>(ao, wof, out);
    }
}

// Round 5
// 272.551 us; speedup vs baseline: 1.2061x; 1.0360x over previous
//
#include <hip/hip_runtime.h>
#include <math.h>

#define BB 4
#define SS 1024
#define DD 1024
#define HH 16
#define DHH 64

typedef _Float16 half8 __attribute__((ext_vector_type(8)));
typedef _Float16 half4v __attribute__((ext_vector_type(4)));
typedef float v4f __attribute__((ext_vector_type(4)));
typedef unsigned int u32;
typedef unsigned short u16;

// async global->LDS, 16B/lane. LDS dest is wave-uniform base + lane*16.
__device__ __forceinline__ void gload_lds16(const void* g, void* l) {
    __builtin_amdgcn_global_load_lds(
        (const __attribute__((address_space(1))) u32*)(const u32*)g,
        (__attribute__((address_space(3))) u32*)(u32*)l, 16, 0, 0);
}

// ---------------------------------------------------------------------------
// convert (small-ws fallback): W_q, W_k(*0.125), W_v, W_o, pe(*8)  (verified)
// ---------------------------------------------------------------------------
__global__ __launch_bounds__(256) void convert_kernel(
    const float* __restrict__ wq, const float* __restrict__ wk,
    const float* __restrict__ wv, const float* __restrict__ wo,
    const float* __restrict__ pe, _Float16* __restrict__ dst)
{
    const int i4 = blockIdx.x * 256 + threadIdx.x;
    const int region = i4 >> 18;
    const int local4 = i4 & 262143;
    const float* srcs[5] = {wq, wk, wv, wo, pe};
    const float scales[5] = {1.0f, 0.125f, 1.0f, 1.0f, 8.0f};
    const float sc = scales[region];
    float4 v = *(const float4*)(srcs[region] + (size_t)local4 * 4);
    half4v h = {(_Float16)(v.x * sc), (_Float16)(v.y * sc),
                (_Float16)(v.z * sc), (_Float16)(v.w * sc)};
    *(half4v*)(dst + ((size_t)region << 20) + (size_t)local4 * 4) = h;
}

// ---------------------------------------------------------------------------
// convert2 (big-ws): regions 0-4 as above; 5-8 query, 9-12 key, 13-16 value
// (fp32 -> f16, scale 1).  Region is block-uniform (1024 blocks/region).
// ---------------------------------------------------------------------------
__global__ __launch_bounds__(256) void convert2_kernel(
    const float* __restrict__ wq, const float* __restrict__ wk,
    const float* __restrict__ wv, const float* __restrict__ wo,
    const float* __restrict__ pe, const float* __restrict__ q,
    const float* __restrict__ k, const float* __restrict__ vv,
    _Float16* __restrict__ dst)
{
    const int i4 = blockIdx.x * 256 + threadIdx.x;
    const int region = i4 >> 18;
    const int local4 = i4 & 262143;
    const float* src;
    float sc = 1.0f;
    if (region == 0)      { src = wq; }
    else if (region == 1) { src = wk; sc = 0.125f; }
    else if (region == 2) { src = wv; }
    else if (region == 3) { src = wo; }
    else if (region == 4) { src = pe; sc = 8.0f; }
    else if (region < 9)  { src = q  + ((size_t)(region - 5)  << 20); }
    else if (region < 13) { src = k  + ((size_t)(region - 9)  << 20); }
    else                  { src = vv + ((size_t)(region - 13) << 20); }
    float4 v = *(const float4*)(src + (size_t)local4 * 4);
    half4v h = {(_Float16)(v.x * sc), (_Float16)(v.y * sc),
                (_Float16)(v.z * sc), (_Float16)(v.w * sc)};
    *(half4v*)(dst + ((size_t)region << 20) + (size_t)local4 * 4) = h;
}

// ---------------------------------------------------------------------------
// Fused Q/K/V projection, fp32-A path (R5-VERIFIED; small-ws fallback)
// ---------------------------------------------------------------------------
__global__ __launch_bounds__(256) void gemm_proj_f32(
    const float* __restrict__ Aq, const float* __restrict__ Ak,
    const float* __restrict__ Av,
    const _Float16* __restrict__ Wqf, const _Float16* __restrict__ Wkf,
    const _Float16* __restrict__ Wvf,
    _Float16* __restrict__ Cq, _Float16* __restrict__ Ck,
    _Float16* __restrict__ Cv)
{
    __shared__ _Float16 As[128 * 32];
    __shared__ _Float16 Bs[64 * 32];

    const int z = blockIdx.z;
    const float* A = z == 0 ? Aq : z == 1 ? Ak : Av;
    const _Float16* W = z == 0 ? Wqf : z == 1 ? Wkf : Wvf;
    _Float16* C = z == 0 ? Cq : z == 1 ? Ck : Cv;

    const int tid = threadIdx.x;
    const int w = tid >> 6, lane = tid & 63, lm = lane & 15, quad = lane >> 4;
    const int n0 = blockIdx.x * 64, m0 = blockIdx.y * 128;

    const int brow = tid >> 2, blc = (tid & 3) ^ (brow & 3);

    v4f zero4 = {0.f, 0.f, 0.f, 0.f};
    v4f acc[2][4];
#pragma unroll
    for (int mi = 0; mi < 2; mi++)
#pragma unroll
        for (int ni = 0; ni < 4; ni++) acc[mi][ni] = zero4;

    for (int k0 = 0; k0 < DD; k0 += 32) {
        __syncthreads();
        gload_lds16(W + (size_t)(n0 + brow) * DD + k0 + blc * 8, Bs + tid * 8);
#pragma unroll
        for (int u = 0; u < 4; u++) {
            int c4 = tid + 256 * u;
            int row = c4 >> 3, k4 = c4 & 7;
            float4 v = *(const float4*)(A + (size_t)(m0 + row) * DD + k0 + k4 * 4);
            half4v hv = {(_Float16)v.x, (_Float16)v.y, (_Float16)v.z, (_Float16)v.w};
            int c16 = k4 >> 1, hlf = k4 & 1;
            *(half4v*)(As + row * 32 + (((c16 ^ (row & 3)) << 3) + (hlf << 2))) = hv;
        }
        __syncthreads();

        half8 af[2], bf[4];
#pragma unroll
        for (int mi = 0; mi < 2; mi++) {
            int row = w * 32 + mi * 16 + lm;
            af[mi] = *(const half8*)(As + row * 32 + ((quad ^ (row & 3)) << 3));
        }
#pragma unroll
        for (int ni = 0; ni < 4; ni++) {
            int row = ni * 16 + lm;
            bf[ni] = *(const half8*)(Bs + row * 32 + ((quad ^ (row & 3)) << 3));
        }
#pragma unroll
        for (int mi = 0; mi < 2; mi++)
#pragma unroll
            for (int ni = 0; ni < 4; ni++)
                acc[mi][ni] = __builtin_amdgcn_mfma_f32_16x16x32_f16(
                    af[mi], bf[ni], acc[mi][ni], 0, 0, 0);
    }

    const int h = n0 >> 6;
#pragma unroll
    for (int mi = 0; mi < 2; mi++)
#pragma unroll
        for (int r = 0; r < 4; r++) {
            int m = m0 + w * 32 + mi * 16 + quad * 4 + r;
            int b = m >> 10, s = m & 1023;
            size_t base = ((size_t)(b * HH + h) * SS + s) * DHH;
#pragma unroll
            for (int ni = 0; ni < 4; ni++)
                C[base + ni * 16 + lm] = (_Float16)acc[mi][ni][r];
        }
}

// ---------------------------------------------------------------------------
// Fused Q/K/V projection, f16-A path, 128x128 tile (R5 new).  m97-structure:
// 2x2 wave grid, each wave a 64x64 sub-tile (4x4 16x16 accs) -> 16 MFMA per
// 8 ds_read_b128 per wave per K-step (vs 8:8 at 128x64).  Staging = verified
// gload_lds16 pattern (pre-swizzled source, linear LDS dest), B extended to
// 128 rows (2 passes, identical to A).  Epilogue index algebra: m = m0 +
// (w>>1)*64 + mi*16 + quad*4 + r; n = n0 + (w&1)*64 + ni*16 + lm; h = n>>6.
// ---------------------------------------------------------------------------
__global__ __launch_bounds__(256) void gemm_proj_f16_128(
    const _Float16* __restrict__ Aq, const _Float16* __restrict__ Ak,
    const _Float16* __restrict__ Av,
    const _Float16* __restrict__ Wqf, const _Float16* __restrict__ Wkf,
    const _Float16* __restrict__ Wvf,
    _Float16* __restrict__ Cq, _Float16* __restrict__ Ck,
    _Float16* __restrict__ Cv)
{
    __shared__ _Float16 As[128 * 32];
    __shared__ _Float16 Bs[128 * 32];

    const int z = blockIdx.z;
    const _Float16* A = z == 0 ? Aq : z == 1 ? Ak : Av;
    const _Float16* W = z == 0 ? Wqf : z == 1 ? Wkf : Wvf;
    _Float16* C = z == 0 ? Cq : z == 1 ? Ck : Cv;

    const int tid = threadIdx.x;
    const int w = tid >> 6, lane = tid & 63, lm = lane & 15, quad = lane >> 4;
    const int wr = (w >> 1) * 64, wc = (w & 1) * 64;
    const int n0 = blockIdx.x * 128, m0 = blockIdx.y * 128;

    v4f zero4 = {0.f, 0.f, 0.f, 0.f};
    v4f acc[4][4];
#pragma unroll
    for (int mi = 0; mi < 4; mi++)
#pragma unroll
        for (int ni = 0; ni < 4; ni++) acc[mi][ni] = zero4;

    for (int k0 = 0; k0 < DD; k0 += 32) {
        __syncthreads();
#pragma unroll
        for (int u = 0; u < 2; u++) {
            int p = tid + 256 * u;
            int row = p >> 2, lc = (p & 3) ^ (row & 3);
            gload_lds16(W + (size_t)(n0 + row) * DD + k0 + lc * 8, Bs + p * 8);
            gload_lds16(A + (size_t)(m0 + row) * DD + k0 + lc * 8, As + p * 8);
        }
        __syncthreads();

        half8 af[4], bf[4];
#pragma unroll
        for (int mi = 0; mi < 4; mi++) {
            int row = wr + mi * 16 + lm;
            af[mi] = *(const half8*)(As + row * 32 + ((quad ^ (row & 3)) << 3));
        }
#pragma unroll
        for (int ni = 0; ni < 4; ni++) {
            int row = wc + ni * 16 + lm;
            bf[ni] = *(const half8*)(Bs + row * 32 + ((quad ^ (row & 3)) << 3));
        }
#pragma unroll
        for (int mi = 0; mi < 4; mi++)
#pragma unroll
            for (int ni = 0; ni < 4; ni++)
                acc[mi][ni] = __builtin_amdgcn_mfma_f32_16x16x32_f16(
                    af[mi], bf[ni], acc[mi][ni], 0, 0, 0);
    }

#pragma unroll
    for (int mi = 0; mi < 4; mi++)
#pragma unroll
        for (int r = 0; r < 4; r++) {
            int m = m0 + wr + mi * 16 + quad * 4 + r;
            int b = m >> 10, s = m & 1023;
#pragma unroll
            for (int ni = 0; ni < 4; ni++) {
                int n = n0 + wc + ni * 16 + lm;
                int h = n >> 6, d = n & 63;
                C[((size_t)(b * HH + h) * SS + s) * DHH + d] = (_Float16)acc[mi][ni][r];
            }
        }
}

// ---------------------------------------------------------------------------
// Output GEMM, 128x128 tile (R5 new): C(fp32 4096x1024) = A(f16) * W^T.
// Same m97-structure as gemm_proj_f16_128; epilogue writes fp32 rows.
// ---------------------------------------------------------------------------
__global__ __launch_bounds__(256) void gemm_out_128(
    const _Float16* __restrict__ A, const _Float16* __restrict__ W,
    float* __restrict__ C)
{
    __shared__ _Float16 As[128 * 32];
    __shared__ _Float16 Bs[128 * 32];

    const int tid = threadIdx.x;
    const int w = tid >> 6, lane = tid & 63, lm = lane & 15, quad = lane >> 4;
    const int wr = (w >> 1) * 64, wc = (w & 1) * 64;
    const int n0 = blockIdx.x * 128, m0 = blockIdx.y * 128;

    v4f zero4 = {0.f, 0.f, 0.f, 0.f};
    v4f acc[4][4];
#pragma unroll
    for (int mi = 0; mi < 4; mi++)
#pragma unroll
        for (int ni = 0; ni < 4; ni++) acc[mi][ni] = zero4;

    for (int k0 = 0; k0 < DD; k0 += 32) {
        __syncthreads();
#pragma unroll
        for (int u = 0; u < 2; u++) {
            int p = tid + 256 * u;
            int row = p >> 2, lc = (p & 3) ^ (row & 3);
            gload_lds16(W + (size_t)(n0 + row) * DD + k0 + lc * 8, Bs + p * 8);
            gload_lds16(A + (size_t)(m0 + row) * DD + k0 + lc * 8, As + p * 8);
        }
        __syncthreads();

        half8 af[4], bf[4];
#pragma unroll
        for (int mi = 0; mi < 4; mi++) {
            int row = wr + mi * 16 + lm;
            af[mi] = *(const half8*)(As + row * 32 + ((quad ^ (row & 3)) << 3));
        }
#pragma unroll
        for (int ni = 0; ni < 4; ni++) {
            int row = wc + ni * 16 + lm;
            bf[ni] = *(const half8*)(Bs + row * 32 + ((quad ^ (row & 3)) << 3));
        }
#pragma unroll
        for (int mi = 0; mi < 4; mi++)
#pragma unroll
            for (int ni = 0; ni < 4; ni++)
                acc[mi][ni] = __builtin_amdgcn_mfma_f32_16x16x32_f16(
                    af[mi], bf[ni], acc[mi][ni], 0, 0, 0);
    }

#pragma unroll
    for (int mi = 0; mi < 4; mi++)
#pragma unroll
        for (int r = 0; r < 4; r++) {
            size_t base = (size_t)(m0 + wr + mi * 16 + quad * 4 + r) * DD
                        + n0 + wc + lm;
#pragma unroll
            for (int ni = 0; ni < 4; ni++)
                C[base + ni * 16] = acc[mi][ni][r];
        }
}

// ---------------------------------------------------------------------------
// Output GEMM, 128x64 tile (R5-VERIFIED; small-ws fallback)
// ---------------------------------------------------------------------------
__global__ __launch_bounds__(256) void gemm_out(
    const _Float16* __restrict__ A, const _Float16* __restrict__ W,
    float* __restrict__ C)
{
    __shared__ _Float16 As[128 * 32];
    __shared__ _Float16 Bs[64 * 32];

    const int tid = threadIdx.x;
    const int w = tid >> 6, lane = tid & 63, lm = lane & 15, quad = lane >> 4;
    const int n0 = blockIdx.x * 64, m0 = blockIdx.y * 128;
    const int brow = tid >> 2, blc = (tid & 3) ^ (brow & 3);

    v4f zero4 = {0.f, 0.f, 0.f, 0.f};
    v4f acc[2][4];
#pragma unroll
    for (int mi = 0; mi < 2; mi++)
#pragma unroll
        for (int ni = 0; ni < 4; ni++) acc[mi][ni] = zero4;

    for (int k0 = 0; k0 < DD; k0 += 32) {
        __syncthreads();
        gload_lds16(W + (size_t)(n0 + brow) * DD + k0 + blc * 8, Bs + tid * 8);
#pragma unroll
        for (int u = 0; u < 2; u++) {
            int p = tid + 256 * u;
            int row = p >> 2, lc = (p & 3) ^ (row & 3);
            gload_lds16(A + (size_t)(m0 + row) * DD + k0 + lc * 8, As + p * 8);
        }
        __syncthreads();

        half8 af[2], bf[4];
#pragma unroll
    for (int mi = 0; mi < 2; mi++) {
            int row = w * 32 + mi * 16 + lm;
            af[mi] = *(const half8*)(As + row * 32 + ((quad ^ (row & 3)) << 3));
        }
#pragma unroll
        for (int ni = 0; ni < 4; ni++) {
            int row = ni * 16 + lm;
            bf[ni] = *(const half8*)(Bs + row * 32 + ((quad ^ (row & 3)) << 3));
        }
#pragma unroll
        for (int mi = 0; mi < 2; mi++)
#pragma unroll
            for (int ni = 0; ni < 4; ni++)
                acc[mi][ni] = __builtin_amdgcn_mfma_f32_16x16x32_f16(
                    af[mi], bf[ni], acc[mi][ni], 0, 0, 0);
    }

#pragma unroll
    for (int mi = 0; mi < 2; mi++)
#pragma unroll
        for (int r = 0; r < 4; r++) {
            size_t base = (size_t)(m0 + w * 32 + mi * 16 + quad * 4 + r) * DD
                        + n0 + lm;
#pragma unroll
            for (int ni = 0; ni < 4; ni++)
                C[base + ni * 16] = acc[mi][ni][r];
        }
}

// ---------------------------------------------------------------------------
// MFMA flash attention — R10 kernel, VERIFIED in R4 (dur 110.5us, MfmaUtil
// 9.1, Occ 19.6).  UNTOUCHED this round (R5 isolates the GEMM tile change).
// ---------------------------------------------------------------------------
__global__ __launch_bounds__(256) void attn_mfma(
    const _Float16* __restrict__ Qg, const _Float16* __restrict__ Kg,
    const _Float16* __restrict__ Vg, const int* __restrict__ mask,
    const _Float16* __restrict__ peg, _Float16* __restrict__ Og)
{
    __shared__ _Float16 Ks[64 * 64];        // 8 KB  swizzled
    __shared__ _Float16 Vt[64 * 64];        // 8 KB  [d][j^swz]
    __shared__ _Float16 PEb[128 * 64];      // 16 KB swizzled
    __shared__ _Float16 Pb[4][16 * 64];     // 8 KB  per-wave P, swizzled

    const int tid = threadIdx.x;
    const int w = tid >> 6, lane = tid & 63;
    const int lm = lane & 15, quad = lane >> 4;

    // load-balance swizzle (bijective): co-resident blocks get spread its
    const int lid = blockIdx.y * 16 + blockIdx.x;
    const int it = ((lid & 15) + ((lid >> 8) << 2)) & 15;
    const int bh = lid >> 4;
    const int i0 = it * 64;
    const int b = bh >> 4, h = bh & 15;

    const _Float16* Qb = Qg + (size_t)bh * SS * DHH;
    const _Float16* Kb = Kg + (size_t)bh * SS * DHH;
    const _Float16* Vb = Vg + (size_t)bh * SS * DHH;
    const _Float16* peh = peg + (size_t)h * SS * DHH;

    float mi_f[4];
#pragma unroll
    for (int r = 0; r < 4; r++)
        mi_f[r] = (float)mask[b * SS + i0 + w * 16 + quad * 4 + r];

    // loop-invariant Q fragments, straight from global (L2-resident)
    half8 qf[2];
#pragma unroll
    for (int kc = 0; kc < 2; kc++)
        qf[kc] = *(const half8*)(Qb + (size_t)(i0 + w * 16 + lm) * DHH
                                 + kc * 32 + quad * 8);

    // per-thread staging indices
    const int srow = tid >> 3, sk8 = tid & 7;
    const int lmx = (lm & 7) << 3;          // read-side XOR for Ks/PEb/Pb

    // ones B-fragment for row-sum MFMA
    half8 ones8 = {(_Float16)1, (_Float16)1, (_Float16)1, (_Float16)1,
                   (_Float16)1, (_Float16)1, (_Float16)1, (_Float16)1};

    v4f zero4 = {0.f, 0.f, 0.f, 0.f};
    float m_run[4];
    v4f oacc[4], lacc;
#pragma unroll
    for (int r = 0; r < 4; r++) m_run[r] = -1e30f;
#pragma unroll
    for (int nb = 0; nb < 4; nb++) oacc[nb] = zero4;
    lacc = zero4;

    // ---- prologue prefetch for jt = 0
    half8 kreg[2], vreg[2], pereg[4];
#pragma unroll
    for (int u = 0; u < 2; u++) {
        int row = srow + 32 * u;
        kreg[u] = *(const half8*)(Kb + (size_t)row * DHH + sk8 * 8);
        vreg[u] = *(const half8*)(Vb + (size_t)row * DHH + sk8 * 8);
    }
    {
        const int g0 = SS - 1 - i0 - 63;               // jt = 0
#pragma unroll
        for (int u = 0; u < 4; u++) {
            int o = srow + 32 * u;
            int g = g0 + o;
            half8 v = {0, 0, 0, 0, 0, 0, 0, 0};
            if (g < SS) v = *(const half8*)(peh + (size_t)g * DHH + sk8 * 8);
            pereg[u] = v;
        }
    }

    for (int jt = 0; jt < SS / 64; jt++) {
        const int j0 = jt * 64;
        const bool do_pe = (jt <= it);
        __syncthreads();                                   // (a) prev-iter reads done

        // ---- commit prefetched regs to LDS (vmcnt wait lands here)
#pragma unroll
        for (int u = 0; u < 2; u++) {
            int row = srow + 32 * u;
            *(half8*)(Ks + row * 64 + ((sk8 * 8) ^ ((row & 7) << 3))) = kreg[u];
        }
#pragma unroll
        for (int u = 0; u < 2; u++) {
            int row = srow + 32 * u;
            int jsw = row ^ (sk8 << 3);                    // Vt col-XOR
#pragma unroll
            for (int e = 0; e < 8; e++) Vt[(sk8 * 8 + e) * 64 + jsw] = vreg[u][e];
        }
        if (do_pe) {
#pragma unroll
            for (int u = 0; u < 4; u++) {
                int o = srow + 32 * u;
                *(half8*)(PEb + o * 64 + ((sk8 * 8) ^ ((o & 7) << 3))) = pereg[u];
            }
        }
        float mj_f[4];
#pragma unroll
        for (int nb = 0; nb < 4; nb++)
            mj_f[nb] = (float)mask[b * SS + j0 + nb * 16 + lm];
        __syncthreads();                                   // (b) staging visible

        // ---- prefetch tile jt+1 into regs (latency hidden under compute)
        if (jt + 1 < SS / 64) {
            const int j0n = j0 + 64;
#pragma unroll
            for (int u = 0; u < 2; u++) {
                int row = srow + 32 * u;
                kreg[u] = *(const half8*)(Kb + (size_t)(j0n + row) * DHH + sk8 * 8);
                vreg[u] = *(const half8*)(Vb + (size_t)(j0n + row) * DHH + sk8 * 8);
            }
            if (jt + 1 <= it) {
                const int g0n = SS - 1 + j0n - i0 - 63;
#pragma unroll
                for (int u = 0; u < 4; u++) {
                    int o = srow + 32 * u;
                    int g = g0n + o;
                    half8 v = {0, 0, 0, 0, 0, 0, 0, 0};
                    if (g < SS) v = *(const half8*)(peh + (size_t)g * DHH + sk8 * 8);
                    pereg[u] = v;
                }
            }
        }

        // ---- QK^T
        v4f sacc[4];
#pragma unroll
        for (int nb = 0; nb < 4; nb++) sacc[nb] = zero4;
        __builtin_amdgcn_s_setprio(1);
#pragma unroll
        for (int nb = 0; nb < 4; nb++)
#pragma unroll
            for (int kc = 0; kc < 2; kc++) {
                half8 kf = *(const half8*)(Ks + (nb * 16 + lm) * 64
                                           + ((kc * 32 + quad * 8) ^ lmx));
                sacc[nb] = __builtin_amdgcn_mfma_f32_16x16x32_f16(qf[kc], kf, sacc[nb], 0, 0, 0);
            }
        __builtin_amdgcn_s_setprio(0);

        // ---- relative position band: 5 tiles + shfl gather
        if (do_pe) {
            v4f racc[5];
#pragma unroll
            for (int e = 0; e < 5; e++) racc[e] = zero4;
            __builtin_amdgcn_s_setprio(1);
#pragma unroll
            for (int e = 0; e < 5; e++) {
                int row = (e + 3 - w) * 16 + lm;
#pragma unroll
                for (int kc = 0; kc < 2; kc++) {
                    half8 pf = *(const half8*)(PEb + row * 64
                                               + ((kc * 32 + quad * 8) ^ lmx));
                    racc[e] = __builtin_amdgcn_mfma_f32_16x16x32_f16(qf[kc], pf, racc[e], 0, 0, 0);
                }
            }
            __builtin_amdgcn_s_setprio(0);
#pragma unroll
            for (int nb = 0; nb < 4; nb++)
#pragma unroll
                for (int r = 0; r < 4; r++) {
                    int qr = quad * 4 + r;
                    float vsrc = (((lm + qr + 1) & 15) <= qr)
                               ? racc[nb][r] : racc[nb + 1][r];
                    int src = (lane & 48) | ((lm - qr - 1) & 15);
                    sacc[nb][r] += __shfl(vsrc, src);
                }
        }

        // ---- mask + online softmax (rmax butterfly only; rsum via MFMA)
        float p[4][4];
        float alpha[4];
#pragma unroll
        for (int i = 0; i < 4; i++) {
            float mi = mi_f[i];
            float rmax = -1e30f;
#pragma unroll
            for (int j = 0; j < 4; j++) {
                float s = sacc[j][i];
                if (mi * mj_f[j] == 0.f) s = -1e9f;
                sacc[j][i] = s;
                rmax = fmaxf(rmax, s);
            }
#pragma unroll
            for (int off = 1; off < 16; off <<= 1)
                rmax = fmaxf(rmax, __shfl_xor(rmax, off));
            float mnew = fmaxf(m_run[i], rmax);
            alpha[i] = __expf(m_run[i] - mnew);
            m_run[i] = mnew;
#pragma unroll
            for (int j = 0; j < 4; j++)
                p[j][i] = __expf(sacc[j][i] - mnew);
        }

        // write P (f16) into dedicated per-wave buffer; rescale O and l.
        // Pb[w] is written+read by wave w only (same-wave RAW via lgkmcnt).
        _Float16* Pw = &Pb[w][0];
#pragma unroll
        for (int nb = 0; nb < 4; nb++)
#pragma unroll
            for (int r = 0; r < 4; r++) {
                int qr = quad * 4 + r;
                Pw[qr * 64 + ((nb * 16 + lm) ^ ((qr & 7) << 3))] = (_Float16)p[nb][r];
            }
#pragma unroll
        for (int nb = 0; nb < 4; nb++)
#pragma unroll
            for (int r = 0; r < 4; r++) oacc[nb][r] *= alpha[r];
#pragma unroll
        for (int r = 0; r < 4; r++) lacc[r] *= alpha[r];

        // ---- PV (+ row-sum MFMA into lacc; pfrag reused)
        __builtin_amdgcn_s_setprio(1);
#pragma unroll
        for (int kc = 0; kc < 2; kc++) {
            half8 pfrag = *(const half8*)(Pw + lm * 64 + ((kc * 32 + quad * 8) ^ lmx));
            lacc = __builtin_amdgcn_mfma_f32_16x16x32_f16(pfrag, ones8, lacc, 0, 0, 0);
#pragma unroll
            for (int nb = 0; nb < 4; nb++) {
                int d = nb * 16 + lm;
                int col = (kc * 32 + quad * 8) ^ (((d >> 3) & 7) << 3);
                half8 vfrag = *(const half8*)(Vt + d * 64 + col);
                oacc[nb] = __builtin_amdgcn_mfma_f32_16x16x32_f16(pfrag, vfrag, oacc[nb], 0, 0, 0);
            }
        }
        __builtin_amdgcn_s_setprio(0);
    }

    // epilogue: normalize, write f16 [B,S,D]
#pragma unroll
    for (int r = 0; r < 4; r++) {
        float inv = 1.f / lacc[r];
        int s = i0 + w * 16 + quad * 4 + r;
#pragma unroll
        for (int nb = 0; nb < 4; nb++)
            Og[((size_t)b * SS + s) * DD + h * DHH + nb * 16 + lm] =
                (_Float16)(oacc[nb][r] * inv);
    }
}

extern "C" void kernel_launch(void* const* d_in, const int* in_sizes, int n_in,
                              void* d_out, int out_size, void* d_ws, size_t ws_size,
                              hipStream_t stream)
{
    const float* query = (const float*)d_in[0];
    const float* key   = (const float*)d_in[1];
    const float* value = (const float*)d_in[2];
    const int*   mask  = (const int*)d_in[3];
    const float* pe    = (const float*)d_in[4];
    const float* Wq    = (const float*)d_in[5];
    const float* Wk    = (const float*)d_in[6];
    const float* Wv    = (const float*)d_in[7];
    const float* Wo    = (const float*)d_in[8];
    float* out = (float*)d_out;

    _Float16* ws16 = (_Float16*)d_ws;
    const size_t MEG = 1048576;
    _Float16* wqf = ws16;
    _Float16* wkf = ws16 + 1 * MEG;
    _Float16* wvf = ws16 + 2 * MEG;
    _Float16* wof = ws16 + 3 * MEG;
    _Float16* pef = ws16 + 4 * MEG;

    const bool big = ws_size >= (size_t)33 * MEG * sizeof(_Float16);

    if (big) {
        // big-ws layout: q16/k16/v16 at 5/9/13; qp/kp/vp at 17/21/25; ao at 29
        _Float16* q16 = ws16 + 5 * MEG;
        _Float16* k16 = ws16 + 9 * MEG;
        _Float16* v16 = ws16 + 13 * MEG;
        _Float16* qp  = ws16 + 17 * MEG;
        _Float16* kp  = ws16 + 21 * MEG;
        _Float16* vp  = ws16 + 25 * MEG;
        _Float16* ao  = ws16 + 29 * MEG;

        convert2_kernel<<<17408, 256, 0, stream>>>(
            Wq, Wk, Wv, Wo, pe, query, key, value, ws16);

        gemm_proj_f16_128<<<dim3(DD / 128, (BB * SS) / 128, 3), 256, 0, stream>>>(
            q16, k16, v16, wqf, wkf, wvf, qp, kp, vp);

        attn_mfma<<<dim3(SS / 64, BB * HH), 256, 0, stream>>>(
            qp, kp, vp, mask, pef, ao);

        gemm_out_128<<<dim3(DD / 128, (BB * SS) / 128), 256, 0, stream>>>(ao, wof, out);
    } else {
        // fallback: original verified layout/path
        _Float16* qp  = ws16 + 5 * MEG;
        _Float16* kp  = ws16 + 9 * MEG;
        _Float16* vp  = ws16 + 13 * MEG;
        _Float16* ao  = ws16 + 17 * MEG;

        convert_kernel<<<5120, 256, 0, stream>>>(Wq, Wk, Wv, Wo, pe, ws16);

        gemm_proj_f32<<<dim3(DD / 64, (BB * SS) / 128, 3), 256, 0, stream>>>(
            query, key, value, wqf, wkf, wvf, qp, kp, vp);

        attn_mfma<<<dim3(SS / 64, BB * HH), 256, 0, stream>>>(
            qp, kp, vp, mask, pef, ao);

        gemm_out<<<dim3(DD / 64, (BB * SS) / 128), 256, 0, stream>>>(ao, wof, out);
    }
}